// Round 8
// baseline (375.582 us; speedup 1.0000x reference)
//
#include <hip/hip_runtime.h>
#include <hip/hip_bf16.h>
#include <math.h>

constexpr int BB = 8, CCH = 192, IH = 128, IW = 128;
constexpr int WSZ = 8;
constexpr int NWIN = 256;
constexpr int NH = 6, HDIM = 32;
constexpr int NPIX = IH * IW;
constexpr int TOPK = 13107;

typedef __attribute__((ext_vector_type(8))) short bf16x8;
typedef __attribute__((ext_vector_type(4))) float f32x4;
typedef __attribute__((ext_vector_type(4))) unsigned short u16x4;
typedef __attribute__((ext_vector_type(8))) unsigned short u16x8;

__device__ __forceinline__ unsigned short f2bf(float f) {
    __hip_bfloat16 h = __float2bfloat16(f);
    return __builtin_bit_cast(unsigned short, h);
}
__device__ __forceinline__ float bf2f(unsigned short u) {
    return __uint_as_float((unsigned)u << 16);
}
__device__ __forceinline__ unsigned monot(float f) {
    unsigned u = __float_as_uint(f);
    return (u & 0x80000000u) ? ~u : (u | 0x80000000u);
}

// ---------------------------------------------------------------------------
// K1: per (b,c) row: exact top-k threshold on var (stable ties like lax.top_k),
//     then masked 8x8 avg-pool + leaky_relu -> pooled (b, c, 16, 16).
//     NO per-thread key array (was spilling to scratch at VGPR=56): keys are
//     recomputed per sweep from var (L2-resident after sweep 1).
// ---------------------------------------------------------------------------
__global__ __launch_bounds__(256) void k1_pool(const float* __restrict__ x,
                                               const float* __restrict__ var,
                                               float* __restrict__ pooled) {
    int row = blockIdx.x;
    const float4* vrow4 = (const float4*)(var + (size_t)row * NPIX);
    const float4* xrow4 = (const float4*)(x + (size_t)row * NPIX);
    int tid = threadIdx.x;
    int wv = tid >> 6, lane = tid & 63;

    __shared__ unsigned histA[4][257];
    __shared__ unsigned histB[4][257];
    __shared__ unsigned s_prefix, s_remaining;
    __shared__ unsigned eq_idx[64];
    __shared__ unsigned eq_cnt;
    __shared__ float wavepart[4][16][16];

    for (int i = tid; i < 4 * 257; i += 256) ((unsigned*)histA)[i] = 0;
    if (tid == 0) eq_cnt = 0;
    __syncthreads();

    unsigned prefix = 0, remaining = TOPK;
    for (int pass = 0; pass < 4; ++pass) {
        int shift = 24 - 8 * pass;
        unsigned (*hcur)[257] = (pass & 1) ? histB : histA;
        unsigned (*hnext)[257] = (pass & 1) ? histA : histB;
#pragma unroll
        for (int j = 0; j < 16; ++j) {
            float4 v4 = vrow4[tid + 256 * j];
            float vv[4] = {v4.x, v4.y, v4.z, v4.w};
#pragma unroll
            for (int c = 0; c < 4; ++c) {
                unsigned mm = monot(vv[c]);
                bool ok = (pass == 0) || ((mm >> (shift + 8)) == prefix);
                if (ok) atomicAdd(&hcur[wv][(mm >> shift) & 255u], 1u);
            }
        }
        __syncthreads();
        if (wv == 0) {
            // lane owns buckets 4*lane..4*lane+3, merged over the 4 wave-hists
            unsigned h[4];
#pragma unroll
            for (int i = 0; i < 4; ++i)
                h[i] = hcur[0][4 * lane + i] + hcur[1][4 * lane + i] +
                       hcur[2][4 * lane + i] + hcur[3][4 * lane + i];
            unsigned lsum = h[0] + h[1] + h[2] + h[3];
            unsigned s = lsum;
#pragma unroll
            for (int off = 1; off < 64; off <<= 1) {
                unsigned t = __shfl(s, lane + off);
                if (lane + off < 64) s += t;
            }
            unsigned snext = s - lsum;      // suffix sum from bucket 4*(lane+1)
            unsigned rem = remaining;
            int cand = -1;
            unsigned candRem = 0;
            unsigned suff = snext;
#pragma unroll
            for (int i = 3; i >= 0; --i) {
                suff += h[i];
                if (cand < 0 && suff >= rem) {
                    cand = 4 * lane + i;
                    candRem = rem - (suff - h[i]);
                }
            }
            unsigned long long bal = __ballot(cand >= 0);
            int src = 63 - __builtin_clzll(bal);
            int bs = __shfl(cand, src);
            unsigned crem = __shfl(candRem, src);
            if (lane == 0) {
                s_prefix = (prefix << 8) | (unsigned)bs;
                s_remaining = crem;
            }
        } else if (wv == 1) {
            for (int i = lane; i < 4 * 257; i += 64) ((unsigned*)hnext)[i] = 0;
        }
        __syncthreads();
        prefix = s_prefix;
        remaining = s_remaining;
    }
    unsigned thr = prefix;
    unsigned need_eq = remaining;

    // tie sweep (stable, ascending indices)
#pragma unroll
    for (int j = 0; j < 16; ++j) {
        float4 v4 = vrow4[tid + 256 * j];
        float vv[4] = {v4.x, v4.y, v4.z, v4.w};
#pragma unroll
        for (int c = 0; c < 4; ++c) {
            if (monot(vv[c]) == thr) {
                unsigned pos = atomicAdd(&eq_cnt, 1u);
                if (pos < 64) eq_idx[pos] = (unsigned)(4 * tid + 1024 * j + c);
            }
        }
    }
    __syncthreads();
    int ecnt = (int)min(eq_cnt, 64u);
    if (tid == 0) {
        for (int a = 1; a < ecnt; ++a) {
            unsigned key = eq_idx[a]; int q = a - 1;
            while (q >= 0 && eq_idx[q] > key) { eq_idx[q + 1] = eq_idx[q]; --q; }
            eq_idx[q + 1] = key;
        }
    }
    __syncthreads();

    // pooling sweep: chunk j of thread t covers window (wy=j, wx=(t>>1)&15)
#pragma unroll
    for (int j = 0; j < 16; ++j) {
        float4 v4 = vrow4[tid + 256 * j];
        float4 x4 = xrow4[tid + 256 * j];
        float vv[4] = {v4.x, v4.y, v4.z, v4.w};
        float xv[4] = {x4.x, x4.y, x4.z, x4.w};
        float part = 0.f;
#pragma unroll
        for (int c = 0; c < 4; ++c) {
            unsigned mm = monot(vv[c]);
            float mult;
            if (mm > thr) mult = 1.0f;
            else if (mm < thr) mult = 0.6f;
            else {
                int i = 4 * tid + 1024 * j + c;
                unsigned rank = 0;
                for (int e = 0; e < ecnt; ++e) if (eq_idx[e] < (unsigned)i) ++rank;
                mult = (rank < need_eq) ? 1.0f : 0.6f;
            }
            part += xv[c] * mult;
        }
        part += __shfl_xor(part, 1);
        part += __shfl_xor(part, 32);
        if ((lane & 1) == 0 && lane < 32) wavepart[wv][j][lane >> 1] = part;
    }
    __syncthreads();
    {
        int j = tid >> 4, ww = tid & 15;
        float s = wavepart[0][j][ww] + wavepart[1][j][ww] +
                  wavepart[2][j][ww] + wavepart[3][j][ww];
        s *= (1.0f / 64.0f);
        float pv = s > 0.f ? s : 0.01f * s;
        pooled[(size_t)row * NWIN + tid] = pv;
    }
}

// ---------------------------------------------------------------------------
// K2: per (b, window): dots with bias_w/scale_w -> sb[p][win] = {sx,sy,bx/16,by/16}
// ---------------------------------------------------------------------------
__global__ __launch_bounds__(64) void k2_sb(const float* __restrict__ pooled,
                                            const float* __restrict__ bias_w,
                                            const float* __restrict__ bias_b,
                                            const float* __restrict__ scale_w,
                                            const float* __restrict__ scale_b,
                                            float* __restrict__ sb) {
    int blk = blockIdx.x;
    int b = blk / NWIN, w = blk % NWIN;
    int tid = threadIdx.x;
    __shared__ float pcol[CCH];
    __shared__ float res[24];
    for (int c = tid; c < CCH; c += 64) pcol[c] = pooled[(size_t)(b * CCH + c) * NWIN + w];
    __syncthreads();
    if (tid < 24) {
        bool isScale = tid >= 12;
        int o = isScale ? tid - 12 : tid;
        const float* Wt = isScale ? scale_w : bias_w;
        float acc = 0.f;
        for (int c = 0; c < CCH; ++c) acc += Wt[o * CCH + c] * pcol[c];
        acc += (isScale ? scale_b[o] : bias_b[o]);
        if (!isScale) acc *= (1.0f / 16.0f);
        res[tid] = acc;
    }
    __syncthreads();
    if (tid < NH) {
        int p = b * NH + tid;
        float4 v;
        v.x = res[12 + 2 * tid];
        v.y = res[12 + 2 * tid + 1];
        v.z = res[2 * tid];
        v.w = res[2 * tid + 1];
        ((float4*)sb)[(size_t)p * NWIN + w] = v;
    }
}

// ---------------------------------------------------------------------------
// KW: convert qkv_w (110592 f32) + proj_w (36864 f32) -> bf16, concatenated.
// ---------------------------------------------------------------------------
__global__ __launch_bounds__(256) void kw_conv(const float* __restrict__ qkv_w,
                                               const float* __restrict__ proj_w,
                                               unsigned short* __restrict__ wbf) {
    int i4 = blockIdx.x * 256 + threadIdx.x;    // 0..36863 float4 units
    float4 v = (i4 < 27648) ? ((const float4*)qkv_w)[i4]
                            : ((const float4*)proj_w)[i4 - 27648];
    u16x4 pk = { f2bf(v.x), f2bf(v.y), f2bf(v.z), f2bf(v.w) };
    ((u16x4*)wbf)[i4] = pk;
}

// ---------------------------------------------------------------------------
// K0X: transpose x (b, c, px) f32 -> xt (b, px, c) bf16, LDS-tiled.
// ---------------------------------------------------------------------------
__global__ __launch_bounds__(256) void k0_xpose(const float* __restrict__ x,
                                                unsigned short* __restrict__ xt) {
    __shared__ unsigned short T[64][200];
    int px0 = blockIdx.x * 64;
    int b = blockIdx.y;
    int tid = threadIdx.x;
    int px = tid & 63, cg = tid >> 6;

#pragma unroll
    for (int j8 = 0; j8 < 6; ++j8) {
        u16x8 pk;
#pragma unroll
        for (int j = 0; j < 8; ++j)
            pk[j] = f2bf(x[(size_t)(b * CCH + cg * 48 + j8 * 8 + j) * NPIX + px0 + px]);
        *(u16x8*)&T[px][cg * 48 + j8 * 8] = pk;
    }
    __syncthreads();
#pragma unroll
    for (int i = 0; i < 6; ++i) {
        int u = tid + 256 * i;
        int p2 = u / 24, cb = u % 24;
        *(u16x8*)&xt[((size_t)(b * NPIX) + px0 + p2) * CCH + cb * 8] = *(const u16x8*)&T[p2][cb * 8];
    }
}

// ---------------------------------------------------------------------------
// K3: qkv 1x1 conv via bf16 MFMA, channel-last outputs:
//     q: (b, px, 192)   k/v: (b*NH+head, px, 32)
// ---------------------------------------------------------------------------
template <bool FAST>
__global__ __launch_bounds__(256) void k3_mfma(const float* __restrict__ x,
                                               const unsigned short* __restrict__ xt,
                                               const unsigned short* __restrict__ wq,
                                               const float* __restrict__ qkv_b,
                                               unsigned short* __restrict__ qb,
                                               unsigned short* __restrict__ kb,
                                               unsigned short* __restrict__ vb) {
    constexpr int BN = 128, KC = 64, KCP = 72;
    __shared__ unsigned short Ws[CCH][KCP];
    __shared__ unsigned short Xt[BN][KCP];
    int px0 = blockIdx.x * BN;
    int t = blockIdx.y, b = blockIdx.z;
    int o0 = t * CCH;
    int tid = threadIdx.x;
    int wv = tid >> 6, lane = tid & 63, lr = lane & 15, lg = lane >> 4;

    f32x4 acc[3][8];
#pragma unroll
    for (int i = 0; i < 3; ++i)
#pragma unroll
        for (int j = 0; j < 8; ++j) acc[i][j] = (f32x4){0.f, 0.f, 0.f, 0.f};

    int spx = tid & 127, skg = tid >> 7;

    for (int k0 = 0; k0 < CCH; k0 += KC) {
#pragma unroll
        for (int i = 0; i < 6; ++i) {
            int u = tid + 256 * i;
            int o = u >> 3, kb8 = u & 7;
            *(u16x8*)&Ws[o][kb8 * 8] = *(const u16x8*)&wq[(size_t)(o0 + o) * CCH + k0 + kb8 * 8];
        }
        if (FAST) {
#pragma unroll
            for (int i = 0; i < 4; ++i) {
                int u = tid + 256 * i;
                int px = u >> 3, kb8 = u & 7;
                *(u16x8*)&Xt[px][kb8 * 8] =
                    *(const u16x8*)&xt[((size_t)(b * NPIX) + px0 + px) * CCH + k0 + kb8 * 8];
            }
        } else {
            const float* xcol = &x[(size_t)(b * CCH + k0 + skg * 32) * NPIX + px0 + spx];
#pragma unroll
            for (int j8 = 0; j8 < 4; ++j8) {
                u16x8 pk;
#pragma unroll
                for (int j = 0; j < 8; ++j) pk[j] = f2bf(xcol[(size_t)(j8 * 8 + j) * NPIX]);
                *(u16x8*)&Xt[spx][skg * 32 + j8 * 8] = pk;
            }
        }
        __syncthreads();
#pragma unroll
        for (int kk = 0; kk < KC; kk += 32) {
            bf16x8 af[3], bfr[8];
#pragma unroll
            for (int i = 0; i < 3; ++i)
                af[i] = *(const bf16x8*)&Ws[wv * 48 + i * 16 + lr][kk + lg * 8];
#pragma unroll
            for (int j = 0; j < 8; ++j)
                bfr[j] = *(const bf16x8*)&Xt[j * 16 + lr][kk + lg * 8];
#pragma unroll
            for (int i = 0; i < 3; ++i)
#pragma unroll
                for (int j = 0; j < 8; ++j)
                    acc[i][j] = __builtin_amdgcn_mfma_f32_16x16x32_bf16(af[i], bfr[j], acc[i][j], 0, 0, 0);
        }
        __syncthreads();
    }

#pragma unroll
    for (int i = 0; i < 3; ++i) {
        int och = wv * 48 + i * 16 + lg * 4;
        float b0 = qkv_b[o0 + och], b1 = qkv_b[o0 + och + 1];
        float b2 = qkv_b[o0 + och + 2], b3 = qkv_b[o0 + och + 3];
#pragma unroll
        for (int j = 0; j < 8; ++j) {
            int px = px0 + lr + j * 16;
            u16x4 pk = { f2bf(acc[i][j][0] + b0), f2bf(acc[i][j][1] + b1),
                         f2bf(acc[i][j][2] + b2), f2bf(acc[i][j][3] + b3) };
            if (t == 0) {
                *(u16x4*)&qb[((size_t)b * NPIX + px) * CCH + och] = pk;
            } else {
                int head = och >> 5, d = och & 31;
                unsigned short* dst = (t == 1) ? kb : vb;
                *(u16x4*)&dst[(((size_t)(b * NH + head)) * NPIX + px) * HDIM + d] = pk;
            }
        }
    }
}

// ---------------------------------------------------------------------------
// K4: wave-per-window MFMA attention. S^T = K_samp . Q^T, softmax in-register,
//     PV via MFMA with P,V in LDS. Writes att (bf16, channel-last) into qb.
// ---------------------------------------------------------------------------
__global__ __launch_bounds__(256) void k4_attn(unsigned short* __restrict__ qatt,
                                               const unsigned short* __restrict__ kb,
                                               const unsigned short* __restrict__ vb,
                                               const float* __restrict__ sb,
                                               const float* __restrict__ rel_table) {
    int tid = threadIdx.x;
    int wv = tid >> 6, lane = tid & 63, lr = lane & 15, lg = lane >> 4;
    int head = blockIdx.y, b = blockIdx.z;
    int win = blockIdx.x * 4 + wv;
    int wy = win >> 4, wx = win & 15;
    int p = b * NH + head;

    __shared__ float rel_s[225];
    __shared__ unsigned short Vl[4][64][33];
    __shared__ unsigned short Pl[4][64][68];

    if (tid < 225) rel_s[tid] = rel_table[tid * NH + head];

    bf16x8 qf[4];
#pragma unroll
    for (int tq = 0; tq < 4; ++tq) {
        int q = tq * 16 + lr;
        int pix = (wy * 8 + (q >> 3)) * IW + wx * 8 + (q & 7);
        qf[tq] = *(const bf16x8*)&qatt[((size_t)b * NPIX + pix) * CCH + head * HDIM + lg * 8];
    }

    float4 sbv = ((const float4*)sb)[(size_t)p * NWIN + win];
    bf16x8 kf[4];
#pragma unroll
    for (int mi = 0; mi < 4; ++mi) {
        int px = mi * 16 + lr;
        int dy = px >> 3, dx = px & 7;
        int yg = wy * 8 + dy, xg = wx * 8 + dx;
        float gx = -1.0f + xg * (2.0f / 127.0f) + ((float)dx - 3.5f) * (2.0f / 127.0f) * sbv.x + sbv.z;
        float gy = -1.0f + yg * (2.0f / 127.0f) + ((float)dy - 3.5f) * (2.0f / 127.0f) * sbv.y + sbv.w;
        float fx = (gx + 1.0f) * 0.5f * 127.0f;
        float fy = (gy + 1.0f) * 0.5f * 127.0f;
        float x0f = floorf(fx), y0f = floorf(fy);
        float wx1 = fx - x0f, wy1 = fy - y0f;
        int ix0 = (int)x0f, iy0 = (int)y0f;
        int ix1 = ix0 + 1, iy1 = iy0 + 1;
        float w00 = (1.0f - wx1) * (1.0f - wy1);
        float w10 = wx1 * (1.0f - wy1);
        float w01 = (1.0f - wx1) * wy1;
        float w11 = wx1 * wy1;
        bool vX0 = (ix0 >= 0) && (ix0 < IW), vX1 = (ix1 >= 0) && (ix1 < IW);
        bool vY0 = (iy0 >= 0) && (iy0 < IH), vY1 = (iy1 >= 0) && (iy1 < IH);
        if (!(vX0 && vY0)) w00 = 0.f;
        if (!(vX1 && vY0)) w10 = 0.f;
        if (!(vX0 && vY1)) w01 = 0.f;
        if (!(vX1 && vY1)) w11 = 0.f;
        int cx0 = min(max(ix0, 0), IW - 1), cx1 = min(max(ix1, 0), IW - 1);
        int cy0 = min(max(iy0, 0), IH - 1), cy1 = min(max(iy1, 0), IH - 1);
        size_t r00 = ((size_t)p * NPIX + cy0 * IW + cx0) * HDIM + lg * 8;
        size_t r10 = ((size_t)p * NPIX + cy0 * IW + cx1) * HDIM + lg * 8;
        size_t r01 = ((size_t)p * NPIX + cy1 * IW + cx0) * HDIM + lg * 8;
        size_t r11 = ((size_t)p * NPIX + cy1 * IW + cx1) * HDIM + lg * 8;
        u16x8 k00 = *(const u16x8*)&kb[r00], k10 = *(const u16x8*)&kb[r10];
        u16x8 k01 = *(const u16x8*)&kb[r01], k11 = *(const u16x8*)&kb[r11];
        u16x8 v00 = *(const u16x8*)&vb[r00], v10 = *(const u16x8*)&vb[r10];
        u16x8 v01 = *(const u16x8*)&vb[r01], v11 = *(const u16x8*)&vb[r11];
#pragma unroll
        for (int c = 0; c < 8; ++c) {
            float kvv = w00 * bf2f(k00[c]) + w10 * bf2f(k10[c]) +
                        w01 * bf2f(k01[c]) + w11 * bf2f(k11[c]);
            float vvv = w00 * bf2f(v00[c]) + w10 * bf2f(v10[c]) +
                        w01 * bf2f(v01[c]) + w11 * bf2f(v11[c]);
            kf[mi][c] = (short)f2bf(kvv);
            Vl[wv][px][lg * 8 + c] = f2bf(vvv);
        }
    }

    f32x4 acc[4][4];
#pragma unroll
    for (int tk = 0; tk < 4; ++tk)
#pragma unroll
        for (int tq = 0; tq < 4; ++tq) acc[tk][tq] = (f32x4){0.f, 0.f, 0.f, 0.f};
#pragma unroll
    for (int tk = 0; tk < 4; ++tk)
#pragma unroll
        for (int tq = 0; tq < 4; ++tq)
            acc[tk][tq] = __builtin_amdgcn_mfma_f32_16x16x32_bf16(kf[tk], qf[tq], acc[tk][tq], 0, 0, 0);

    __syncthreads();

    const float scale = 0.17677669529663688f;
    int qh[4], qwv[4];
#pragma unroll
    for (int tq = 0; tq < 4; ++tq) { int q = tq * 16 + lr; qh[tq] = q >> 3; qwv[tq] = q & 7; }
    float mx[4] = {-1e30f, -1e30f, -1e30f, -1e30f};
#pragma unroll
    for (int tk = 0; tk < 4; ++tk)
#pragma unroll
        for (int r = 0; r < 4; ++r) {
            int key = tk * 16 + lg * 4 + r;
            int kh = key >> 3, kw = key & 7;
#pragma unroll
            for (int tq = 0; tq < 4; ++tq) {
                float v = acc[tk][tq][r] * scale + rel_s[(qh[tq] - kh + 7) * 15 + (qwv[tq] - kw + 7)];
                acc[tk][tq][r] = v;
                mx[tq] = fmaxf(mx[tq], v);
            }
        }
#pragma unroll
    for (int tq = 0; tq < 4; ++tq) {
        mx[tq] = fmaxf(mx[tq], __shfl_xor(mx[tq], 16));
        mx[tq] = fmaxf(mx[tq], __shfl_xor(mx[tq], 32));
    }
    float sm[4] = {0.f, 0.f, 0.f, 0.f};
#pragma unroll
    for (int tk = 0; tk < 4; ++tk)
#pragma unroll
        for (int tq = 0; tq < 4; ++tq)
#pragma unroll
            for (int r = 0; r < 4; ++r) {
                float e = __expf(acc[tk][tq][r] - mx[tq]);
                acc[tk][tq][r] = e;
                sm[tq] += e;
            }
    float inv[4];
#pragma unroll
    for (int tq = 0; tq < 4; ++tq) {
        float s = sm[tq];
        s += __shfl_xor(s, 16);
        s += __shfl_xor(s, 32);
        inv[tq] = 1.0f / s;
    }
#pragma unroll
    for (int tq = 0; tq < 4; ++tq)
#pragma unroll
        for (int tk = 0; tk < 4; ++tk) {
            u16x4 pk = { f2bf(acc[tk][tq][0] * inv[tq]), f2bf(acc[tk][tq][1] * inv[tq]),
                         f2bf(acc[tk][tq][2] * inv[tq]), f2bf(acc[tk][tq][3] * inv[tq]) };
            *(u16x4*)&Pl[wv][tq * 16 + lr][tk * 16 + lg * 4] = pk;
        }

    __syncthreads();

    f32x4 o[4][2];
#pragma unroll
    for (int mq = 0; mq < 4; ++mq)
#pragma unroll
        for (int nd = 0; nd < 2; ++nd) o[mq][nd] = (f32x4){0.f, 0.f, 0.f, 0.f};
#pragma unroll
    for (int ks = 0; ks < 2; ++ks) {
        bf16x8 Af[4];
#pragma unroll
        for (int mq = 0; mq < 4; ++mq) {
            u16x4 lo = *(const u16x4*)&Pl[wv][mq * 16 + lr][ks * 32 + lg * 8];
            u16x4 hi = *(const u16x4*)&Pl[wv][mq * 16 + lr][ks * 32 + lg * 8 + 4];
#pragma unroll
            for (int c = 0; c < 4; ++c) { Af[mq][c] = (short)lo[c]; Af[mq][c + 4] = (short)hi[c]; }
        }
        bf16x8 Bf[2];
#pragma unroll
        for (int nd = 0; nd < 2; ++nd)
#pragma unroll
            for (int j = 0; j < 8; ++j)
                Bf[nd][j] = (short)Vl[wv][ks * 32 + lg * 8 + j][nd * 16 + lr];
#pragma unroll
        for (int mq = 0; mq < 4; ++mq)
#pragma unroll
            for (int nd = 0; nd < 2; ++nd)
                o[mq][nd] = __builtin_amdgcn_mfma_f32_16x16x32_bf16(Af[mq], Bf[nd], o[mq][nd], 0, 0, 0);
    }

#pragma unroll
    for (int mq = 0; mq < 4; ++mq)
#pragma unroll
        for (int nd = 0; nd < 2; ++nd)
#pragma unroll
            for (int r = 0; r < 4; ++r) {
                int q = mq * 16 + lg * 4 + r;
                int pix = (wy * 8 + (q >> 3)) * IW + wx * 8 + (q & 7);
                qatt[((size_t)b * NPIX + pix) * CCH + head * HDIM + nd * 16 + lr] = f2bf(o[mq][nd][r]);
            }
}

// ---------------------------------------------------------------------------
// K5: projection via bf16 MFMA: out = proj_w(bf16) @ att + proj_b.
// ---------------------------------------------------------------------------
__global__ __launch_bounds__(256) void k5_mfma(const unsigned short* __restrict__ att,
                                               const unsigned short* __restrict__ wp,
                                               const float* __restrict__ proj_b,
                                               float* __restrict__ out) {
    constexpr int BN = 128, KC = 64, KCP = 72;
    __shared__ unsigned short Ws[CCH][KCP];
    __shared__ unsigned short Xt[BN][KCP];
    int px0 = blockIdx.x * BN;
    int b = blockIdx.y;
    int tid = threadIdx.x;
    int wv = tid >> 6, lane = tid & 63, lr = lane & 15, lg = lane >> 4;

    f32x4 acc[3][8];
#pragma unroll
    for (int i = 0; i < 3; ++i)
#pragma unroll
        for (int j = 0; j < 8; ++j) acc[i][j] = (f32x4){0.f, 0.f, 0.f, 0.f};

    int spx = tid & 127, skg = tid >> 7;

    for (int k0 = 0; k0 < CCH; k0 += KC) {
#pragma unroll
        for (int i = 0; i < 6; ++i) {
            int u = tid + 256 * i;
            int o = u >> 3, kb8 = u & 7;
            *(u16x8*)&Ws[o][kb8 * 8] = *(const u16x8*)&wp[(size_t)o * CCH + k0 + kb8 * 8];
        }
        {
            const unsigned short* arow = &att[((size_t)b * NPIX + px0 + spx) * CCH + k0 + skg * 32];
#pragma unroll
            for (int j8 = 0; j8 < 4; ++j8)
                *(u16x8*)&Xt[spx][skg * 32 + j8 * 8] = *(const u16x8*)&arow[j8 * 8];
        }
        __syncthreads();
#pragma unroll
        for (int kk = 0; kk < KC; kk += 32) {
            bf16x8 af[3], bfr[8];
#pragma unroll
            for (int i = 0; i < 3; ++i)
                af[i] = *(const bf16x8*)&Ws[wv * 48 + i * 16 + lr][kk + lg * 8];
#pragma unroll
            for (int j = 0; j < 8; ++j)
                bfr[j] = *(const bf16x8*)&Xt[j * 16 + lr][kk + lg * 8];
#pragma unroll
            for (int i = 0; i < 3; ++i)
#pragma unroll
                for (int j = 0; j < 8; ++j)
                    acc[i][j] = __builtin_amdgcn_mfma_f32_16x16x32_bf16(af[i], bfr[j], acc[i][j], 0, 0, 0);
        }
        __syncthreads();
    }

#pragma unroll
    for (int i = 0; i < 3; ++i) {
        int och = wv * 48 + i * 16 + lg * 4;
#pragma unroll
        for (int r = 0; r < 4; ++r) {
            float bias = proj_b[och + r];
            size_t base = (size_t)(b * CCH + och + r) * NPIX + px0 + lr;
#pragma unroll
            for (int j = 0; j < 8; ++j)
                out[base + j * 16] = acc[i][j][r] + bias;
        }
    }
}

// ---------------------------------------------------------------------------
extern "C" void kernel_launch(void* const* d_in, const int* in_sizes, int n_in,
                              void* d_out, int out_size, void* d_ws, size_t ws_size,
                              hipStream_t stream) {
    const float* x = (const float*)d_in[0];
    const float* var = (const float*)d_in[1];
    const float* qkv_w = (const float*)d_in[2];
    const float* qkv_b = (const float*)d_in[3];
    const float* bias_w = (const float*)d_in[4];
    const float* bias_b = (const float*)d_in[5];
    const float* scale_w = (const float*)d_in[6];
    const float* scale_b = (const float*)d_in[7];
    const float* proj_w = (const float*)d_in[8];
    const float* proj_b = (const float*)d_in[9];
    const float* rel_table = (const float*)d_in[10];
    float* out = (float*)d_out;

    char* ws = (char*)d_ws;
    float* pooled = (float*)ws;                           // 1,572,864 B
    float* sb = (float*)(ws + 1572864ull);                // 196,608 B
    unsigned short* wbf = (unsigned short*)ws;            // overlaps pooled (k2 done first)
    unsigned short* wq_bf = wbf;
    unsigned short* wp_bf = wbf + 110592;
    const size_t elemQ = (size_t)BB * CCH * NPIX;         // 25,165,824
    unsigned short* q = (unsigned short*)(ws + 1769472ull);
    unsigned short* k = q + elemQ;
    unsigned short* v = k + elemQ;
    unsigned short* xt = v + elemQ;

    size_t need_base = 1769472ull + 3ull * elemQ * 2;
    size_t need_fast = 1769472ull + 4ull * elemQ * 2;
    if (ws_size < need_base) return;
    bool fast = ws_size >= need_fast;

    k1_pool<<<dim3(BB * CCH), dim3(256), 0, stream>>>(x, var, pooled);
    k2_sb<<<dim3(BB * NWIN), dim3(64), 0, stream>>>(pooled, bias_w, bias_b, scale_w, scale_b, sb);
    kw_conv<<<dim3(144), dim3(256), 0, stream>>>(qkv_w, proj_w, wbf);
    if (fast) {
        k0_xpose<<<dim3(NPIX / 64, BB), dim3(256), 0, stream>>>(x, xt);
        k3_mfma<true><<<dim3(NPIX / 128, 3, BB), dim3(256), 0, stream>>>(x, xt, wq_bf, qkv_b, q, k, v);
    } else {
        k3_mfma<false><<<dim3(NPIX / 128, 3, BB), dim3(256), 0, stream>>>(x, xt, wq_bf, qkv_b, q, k, v);
    }
    k4_attn<<<dim3(NWIN / 4, NH, BB), dim3(256), 0, stream>>>(q, k, v, sb, rel_table);
    k5_mfma<<<dim3(NPIX / 128, BB), dim3(256), 0, stream>>>(q, wp_bf, proj_b, out);
}

// Round 9
// 336.930 us; speedup vs baseline: 1.1147x; 1.1147x over previous
//
#include <hip/hip_runtime.h>
#include <hip/hip_bf16.h>
#include <math.h>

constexpr int BB = 8, CCH = 192, IH = 128, IW = 128;
constexpr int WSZ = 8;
constexpr int NWIN = 256;
constexpr int NH = 6, HDIM = 32;
constexpr int NPIX = IH * IW;
constexpr int TOPK = 13107;

typedef __attribute__((ext_vector_type(8))) short bf16x8;
typedef __attribute__((ext_vector_type(4))) float f32x4;
typedef __attribute__((ext_vector_type(4))) unsigned short u16x4;
typedef __attribute__((ext_vector_type(8))) unsigned short u16x8;

__device__ __forceinline__ unsigned short f2bf(float f) {
    __hip_bfloat16 h = __float2bfloat16(f);
    return __builtin_bit_cast(unsigned short, h);
}
__device__ __forceinline__ float bf2f(unsigned short u) {
    return __uint_as_float((unsigned)u << 16);
}
__device__ __forceinline__ unsigned monot(float f) {
    unsigned u = __float_as_uint(f);
    return (u & 0x80000000u) ? ~u : (u | 0x80000000u);
}

// ---------------------------------------------------------------------------
// K1: per (b,c) row: exact top-k threshold on var (stable ties like lax.top_k),
//     then masked 8x8 avg-pool + leaky_relu -> pooled (b, c, 16, 16).
//     ONE 12-bit histogram pass (2 copies, low-conflict) + candidate refine.
// ---------------------------------------------------------------------------
__global__ __launch_bounds__(256) void k1_pool(const float* __restrict__ x,
                                               const float* __restrict__ var,
                                               float* __restrict__ pooled) {
    int row = blockIdx.x;
    const float4* vrow4 = (const float4*)(var + (size_t)row * NPIX);
    const float4* xrow4 = (const float4*)(x + (size_t)row * NPIX);
    int tid = threadIdx.x;
    int wv = tid >> 6, lane = tid & 63;

    constexpr int CAP = 320;
    __shared__ unsigned hist2k[2][4096];      // 32 KB, copies by lane&1
    __shared__ unsigned hist256[256];         // fallback refinement
    __shared__ unsigned wtot[4];
    __shared__ unsigned s_prefix, s_rem, s_cnt, s_thr, s_need;
    __shared__ unsigned candKey[CAP], candIdx[CAP];
    __shared__ unsigned cand_cnt, eq_cnt;
    __shared__ unsigned eq_idx[64];
    __shared__ float wavepart[4][16][16];

    for (int i = tid; i < 2 * 4096; i += 256) ((unsigned*)hist2k)[i] = 0;
    if (tid == 0) { cand_cnt = 0; eq_cnt = 0; }
    __syncthreads();

    // ---- pass 0: 12-bit histogram (single sweep) ----
    int hc = lane & 1;
#pragma unroll
    for (int j = 0; j < 16; ++j) {
        float4 v4 = vrow4[tid + 256 * j];
        float vv[4] = {v4.x, v4.y, v4.z, v4.w};
#pragma unroll
        for (int c = 0; c < 4; ++c)
            atomicAdd(&hist2k[hc][monot(vv[c]) >> 20], 1u);
    }
    __syncthreads();

    // ---- scan 4096 buckets: thread owns [16*tid, 16*tid+15] ----
    {
        unsigned h16[16]; unsigned tsum = 0;
#pragma unroll
        for (int i = 0; i < 16; ++i) {
            h16[i] = hist2k[0][tid * 16 + i] + hist2k[1][tid * 16 + i];
            tsum += h16[i];
        }
        unsigned s = tsum;                      // inclusive suffix within wave
#pragma unroll
        for (int off = 1; off < 64; off <<= 1) {
            unsigned t = __shfl(s, lane + off);
            if (lane + off < 64) s += t;
        }
        if (lane == 0) wtot[wv] = s;            // wave total
        __syncthreads();
        unsigned crossTot = 0;
        for (int w = wv + 1; w < 4; ++w) crossTot += wtot[w];
        unsigned above = crossTot + (s - tsum); // count in buckets above my group
        unsigned rem = TOPK;
        if (above < rem && above + tsum >= rem) {
            unsigned cum = above;
            for (int i = 15; i >= 0; --i) {
                if (cum < rem && cum + h16[i] >= rem) {
                    s_prefix = (unsigned)(tid * 16 + i);
                    s_rem = rem - cum;
                    s_cnt = h16[i];
                }
                cum += h16[i];
            }
        }
    }
    __syncthreads();

    unsigned prefix = s_prefix, rem2 = s_rem, cnt = s_cnt;
    int prefbits = 12;

    // ---- fallback refinement (normally 0 iterations) ----
    while (cnt > CAP && prefbits < 32) {
        int nb = (32 - prefbits >= 8) ? 8 : (32 - prefbits);
        int nbuck = 1 << nb;
        __syncthreads();
        for (int i = tid; i < nbuck; i += 256) hist256[i] = 0;
        __syncthreads();
        int shift = 32 - prefbits - nb;
#pragma unroll
        for (int j = 0; j < 16; ++j) {
            float4 v4 = vrow4[tid + 256 * j];
            float vv[4] = {v4.x, v4.y, v4.z, v4.w};
#pragma unroll
            for (int c = 0; c < 4; ++c) {
                unsigned mm = monot(vv[c]);
                if ((mm >> (nb + shift)) == prefix)
                    atomicAdd(&hist256[(mm >> shift) & (nbuck - 1)], 1u);
            }
        }
        __syncthreads();
        if (wv == 0) {
            int bpl = nbuck > 64 ? nbuck / 64 : 1;   // buckets per lane (<=4)
            int nlanes = nbuck / bpl;
            unsigned hh[4] = {0, 0, 0, 0};
            unsigned lsum = 0;
#pragma unroll
            for (int i = 0; i < 4; ++i) {
                if (i < bpl && lane < nlanes) hh[i] = hist256[lane * bpl + i];
                lsum += hh[i];
            }
            unsigned s = lsum;
#pragma unroll
            for (int off = 1; off < 64; off <<= 1) {
                unsigned t = __shfl(s, lane + off);
                if (lane + off < 64) s += t;
            }
            unsigned above = s - lsum;
            if (lane < nlanes && above < rem2 && above + lsum >= rem2) {
                unsigned cum = above;
                for (int i = bpl - 1; i >= 0; --i) {
                    if (cum < rem2 && cum + hh[i] >= rem2) {
                        s_prefix = (prefix << nb) | (unsigned)(lane * bpl + i);
                        s_rem = rem2 - cum;
                        s_cnt = hh[i];
                    }
                    cum += hh[i];
                }
            }
        }
        __syncthreads();
        prefix = s_prefix; rem2 = s_rem; cnt = s_cnt;
        prefbits += nb;
    }

    unsigned thr, need_eq;
    if (prefbits >= 32 && cnt > CAP) {
        // >CAP identical keys: threshold is the full key itself
        thr = prefix;
        need_eq = rem2;
#pragma unroll
        for (int j = 0; j < 16; ++j) {
            float4 v4 = vrow4[tid + 256 * j];
            float vv[4] = {v4.x, v4.y, v4.z, v4.w};
#pragma unroll
            for (int c = 0; c < 4; ++c)
                if (monot(vv[c]) == thr) {
                    unsigned pos = atomicAdd(&eq_cnt, 1u);
                    if (pos < 64) eq_idx[pos] = (unsigned)(4 * tid + 1024 * j + c);
                }
        }
        __syncthreads();
    } else {
        // ---- collect candidates with the selected prefix ----
        int pshift = 32 - prefbits;
#pragma unroll
        for (int j = 0; j < 16; ++j) {
            float4 v4 = vrow4[tid + 256 * j];
            float vv[4] = {v4.x, v4.y, v4.z, v4.w};
#pragma unroll
            for (int c = 0; c < 4; ++c) {
                unsigned mm = monot(vv[c]);
                if ((mm >> pshift) == prefix) {
                    unsigned pos = atomicAdd(&cand_cnt, 1u);
                    if (pos < CAP) {
                        candKey[pos] = mm;
                        candIdx[pos] = (unsigned)(4 * tid + 1024 * j + c);
                    }
                }
            }
        }
        __syncthreads();
        int cc = (int)min(cand_cnt, (unsigned)CAP);
        // exact threshold among candidates via rank (LDS broadcast reads)
        for (int ci = tid; ci < cc; ci += 256) {
            unsigned my = candKey[ci];
            unsigned kgt = 0, keq = 0;
            for (int e = 0; e < cc; ++e) {
                unsigned o = candKey[e];
                kgt += (o > my);
                keq += (o == my);
            }
            if (kgt < rem2 && kgt + keq >= rem2) {
                s_thr = my;
                s_need = rem2 - kgt;
            }
        }
        __syncthreads();
        thr = s_thr;
        need_eq = s_need;
        for (int ci = tid; ci < cc; ci += 256)
            if (candKey[ci] == thr) {
                unsigned pos = atomicAdd(&eq_cnt, 1u);
                if (pos < 64) eq_idx[pos] = candIdx[ci];
            }
        __syncthreads();
    }

    int ecnt = (int)min(eq_cnt, 64u);
    if (tid == 0) {
        for (int a = 1; a < ecnt; ++a) {
            unsigned key = eq_idx[a]; int q = a - 1;
            while (q >= 0 && eq_idx[q] > key) { eq_idx[q + 1] = eq_idx[q]; --q; }
            eq_idx[q + 1] = key;
        }
    }
    __syncthreads();

    // ---- pooling sweep: chunk j of thread t covers window (wy=j, wx=(t>>1)&15) ----
#pragma unroll
    for (int j = 0; j < 16; ++j) {
        float4 v4 = vrow4[tid + 256 * j];
        float4 x4 = xrow4[tid + 256 * j];
        float vv[4] = {v4.x, v4.y, v4.z, v4.w};
        float xv[4] = {x4.x, x4.y, x4.z, x4.w};
        float part = 0.f;
#pragma unroll
        for (int c = 0; c < 4; ++c) {
            unsigned mm = monot(vv[c]);
            float mult;
            if (mm > thr) mult = 1.0f;
            else if (mm < thr) mult = 0.6f;
            else {
                int i = 4 * tid + 1024 * j + c;
                unsigned rank = 0;
                for (int e = 0; e < ecnt; ++e) if (eq_idx[e] < (unsigned)i) ++rank;
                mult = (rank < need_eq) ? 1.0f : 0.6f;
            }
            part += xv[c] * mult;
        }
        part += __shfl_xor(part, 1);
        part += __shfl_xor(part, 32);
        if ((lane & 1) == 0 && lane < 32) wavepart[wv][j][lane >> 1] = part;
    }
    __syncthreads();
    {
        int j = tid >> 4, ww = tid & 15;
        float s = wavepart[0][j][ww] + wavepart[1][j][ww] +
                  wavepart[2][j][ww] + wavepart[3][j][ww];
        s *= (1.0f / 64.0f);
        float pv = s > 0.f ? s : 0.01f * s;
        pooled[(size_t)row * NWIN + tid] = pv;
    }
}

// ---------------------------------------------------------------------------
// K2: per (b, window): dots with bias_w/scale_w -> sb[p][win] = {sx,sy,bx/16,by/16}
// ---------------------------------------------------------------------------
__global__ __launch_bounds__(64) void k2_sb(const float* __restrict__ pooled,
                                            const float* __restrict__ bias_w,
                                            const float* __restrict__ bias_b,
                                            const float* __restrict__ scale_w,
                                            const float* __restrict__ scale_b,
                                            float* __restrict__ sb) {
    int blk = blockIdx.x;
    int b = blk / NWIN, w = blk % NWIN;
    int tid = threadIdx.x;
    __shared__ float pcol[CCH];
    __shared__ float res[24];
    for (int c = tid; c < CCH; c += 64) pcol[c] = pooled[(size_t)(b * CCH + c) * NWIN + w];
    __syncthreads();
    if (tid < 24) {
        bool isScale = tid >= 12;
        int o = isScale ? tid - 12 : tid;
        const float* Wt = isScale ? scale_w : bias_w;
        float acc = 0.f;
        for (int c = 0; c < CCH; ++c) acc += Wt[o * CCH + c] * pcol[c];
        acc += (isScale ? scale_b[o] : bias_b[o]);
        if (!isScale) acc *= (1.0f / 16.0f);
        res[tid] = acc;
    }
    __syncthreads();
    if (tid < NH) {
        int p = b * NH + tid;
        float4 v;
        v.x = res[12 + 2 * tid];
        v.y = res[12 + 2 * tid + 1];
        v.z = res[2 * tid];
        v.w = res[2 * tid + 1];
        ((float4*)sb)[(size_t)p * NWIN + w] = v;
    }
}

// ---------------------------------------------------------------------------
// KW: convert qkv_w (110592 f32) + proj_w (36864 f32) -> bf16, concatenated.
// ---------------------------------------------------------------------------
__global__ __launch_bounds__(256) void kw_conv(const float* __restrict__ qkv_w,
                                               const float* __restrict__ proj_w,
                                               unsigned short* __restrict__ wbf) {
    int i4 = blockIdx.x * 256 + threadIdx.x;
    float4 v = (i4 < 27648) ? ((const float4*)qkv_w)[i4]
                            : ((const float4*)proj_w)[i4 - 27648];
    u16x4 pk = { f2bf(v.x), f2bf(v.y), f2bf(v.z), f2bf(v.w) };
    ((u16x4*)wbf)[i4] = pk;
}

// ---------------------------------------------------------------------------
// K0X: transpose x (b, c, px) f32 -> xt (b, px, c) bf16, LDS-tiled.
// ---------------------------------------------------------------------------
__global__ __launch_bounds__(256) void k0_xpose(const float* __restrict__ x,
                                                unsigned short* __restrict__ xt) {
    __shared__ unsigned short T[64][200];
    int px0 = blockIdx.x * 64;
    int b = blockIdx.y;
    int tid = threadIdx.x;
    int px = tid & 63, cg = tid >> 6;

#pragma unroll
    for (int j8 = 0; j8 < 6; ++j8) {
        u16x8 pk;
#pragma unroll
        for (int j = 0; j < 8; ++j)
            pk[j] = f2bf(x[(size_t)(b * CCH + cg * 48 + j8 * 8 + j) * NPIX + px0 + px]);
        *(u16x8*)&T[px][cg * 48 + j8 * 8] = pk;
    }
    __syncthreads();
#pragma unroll
    for (int i = 0; i < 6; ++i) {
        int u = tid + 256 * i;
        int p2 = u / 24, cb = u % 24;
        *(u16x8*)&xt[((size_t)(b * NPIX) + px0 + p2) * CCH + cb * 8] = *(const u16x8*)&T[p2][cb * 8];
    }
}

// ---------------------------------------------------------------------------
// K3: qkv 1x1 conv via bf16 MFMA, channel-last outputs:
//     q: (b, px, 192)   k/v: (b*NH+head, px, 32)
// ---------------------------------------------------------------------------
template <bool FAST>
__global__ __launch_bounds__(256) void k3_mfma(const float* __restrict__ x,
                                               const unsigned short* __restrict__ xt,
                                               const unsigned short* __restrict__ wq,
                                               const float* __restrict__ qkv_b,
                                               unsigned short* __restrict__ qb,
                                               unsigned short* __restrict__ kb,
                                               unsigned short* __restrict__ vb) {
    constexpr int BN = 128, KC = 64, KCP = 72;
    __shared__ unsigned short Ws[CCH][KCP];
    __shared__ unsigned short Xt[BN][KCP];
    int px0 = blockIdx.x * BN;
    int t = blockIdx.y, b = blockIdx.z;
    int o0 = t * CCH;
    int tid = threadIdx.x;
    int wv = tid >> 6, lane = tid & 63, lr = lane & 15, lg = lane >> 4;

    f32x4 acc[3][8];
#pragma unroll
    for (int i = 0; i < 3; ++i)
#pragma unroll
        for (int j = 0; j < 8; ++j) acc[i][j] = (f32x4){0.f, 0.f, 0.f, 0.f};

    int spx = tid & 127, skg = tid >> 7;

    for (int k0 = 0; k0 < CCH; k0 += KC) {
#pragma unroll
        for (int i = 0; i < 6; ++i) {
            int u = tid + 256 * i;
            int o = u >> 3, kb8 = u & 7;
            *(u16x8*)&Ws[o][kb8 * 8] = *(const u16x8*)&wq[(size_t)(o0 + o) * CCH + k0 + kb8 * 8];
        }
        if (FAST) {
#pragma unroll
            for (int i = 0; i < 4; ++i) {
                int u = tid + 256 * i;
                int px = u >> 3, kb8 = u & 7;
                *(u16x8*)&Xt[px][kb8 * 8] =
                    *(const u16x8*)&xt[((size_t)(b * NPIX) + px0 + px) * CCH + k0 + kb8 * 8];
            }
        } else {
            const float* xcol = &x[(size_t)(b * CCH + k0 + skg * 32) * NPIX + px0 + spx];
#pragma unroll
            for (int j8 = 0; j8 < 4; ++j8) {
                u16x8 pk;
#pragma unroll
                for (int j = 0; j < 8; ++j) pk[j] = f2bf(xcol[(size_t)(j8 * 8 + j) * NPIX]);
                *(u16x8*)&Xt[spx][skg * 32 + j8 * 8] = pk;
            }
        }
        __syncthreads();
#pragma unroll
        for (int kk = 0; kk < KC; kk += 32) {
            bf16x8 af[3], bfr[8];
#pragma unroll
            for (int i = 0; i < 3; ++i)
                af[i] = *(const bf16x8*)&Ws[wv * 48 + i * 16 + lr][kk + lg * 8];
#pragma unroll
            for (int j = 0; j < 8; ++j)
                bfr[j] = *(const bf16x8*)&Xt[j * 16 + lr][kk + lg * 8];
#pragma unroll
            for (int i = 0; i < 3; ++i)
#pragma unroll
                for (int j = 0; j < 8; ++j)
                    acc[i][j] = __builtin_amdgcn_mfma_f32_16x16x32_bf16(af[i], bfr[j], acc[i][j], 0, 0, 0);
        }
        __syncthreads();
    }

#pragma unroll
    for (int i = 0; i < 3; ++i) {
        int och = wv * 48 + i * 16 + lg * 4;
        float b0 = qkv_b[o0 + och], b1 = qkv_b[o0 + och + 1];
        float b2 = qkv_b[o0 + och + 2], b3 = qkv_b[o0 + och + 3];
#pragma unroll
        for (int j = 0; j < 8; ++j) {
            int px = px0 + lr + j * 16;
            u16x4 pk = { f2bf(acc[i][j][0] + b0), f2bf(acc[i][j][1] + b1),
                         f2bf(acc[i][j][2] + b2), f2bf(acc[i][j][3] + b3) };
            if (t == 0) {
                *(u16x4*)&qb[((size_t)b * NPIX + px) * CCH + och] = pk;
            } else {
                int head = och >> 5, d = och & 31;
                unsigned short* dst = (t == 1) ? kb : vb;
                *(u16x4*)&dst[(((size_t)(b * NH + head)) * NPIX + px) * HDIM + d] = pk;
            }
        }
    }
}

// ---------------------------------------------------------------------------
// K4: wave-per-window MFMA attention. S^T = K_samp . Q^T, softmax in-register,
//     PV via MFMA with P,V in LDS. Writes att (bf16, channel-last) into qb.
// ---------------------------------------------------------------------------
__global__ __launch_bounds__(256) void k4_attn(unsigned short* __restrict__ qatt,
                                               const unsigned short* __restrict__ kb,
                                               const unsigned short* __restrict__ vb,
                                               const float* __restrict__ sb,
                                               const float* __restrict__ rel_table) {
    int tid = threadIdx.x;
    int wv = tid >> 6, lane = tid & 63, lr = lane & 15, lg = lane >> 4;
    int head = blockIdx.y, b = blockIdx.z;
    int win = blockIdx.x * 4 + wv;
    int wy = win >> 4, wx = win & 15;
    int p = b * NH + head;

    __shared__ float rel_s[225];
    __shared__ unsigned short Vl[4][64][33];
    __shared__ unsigned short Pl[4][64][68];

    if (tid < 225) rel_s[tid] = rel_table[tid * NH + head];

    bf16x8 qf[4];
#pragma unroll
    for (int tq = 0; tq < 4; ++tq) {
        int q = tq * 16 + lr;
        int pix = (wy * 8 + (q >> 3)) * IW + wx * 8 + (q & 7);
        qf[tq] = *(const bf16x8*)&qatt[((size_t)b * NPIX + pix) * CCH + head * HDIM + lg * 8];
    }

    float4 sbv = ((const float4*)sb)[(size_t)p * NWIN + win];
    bf16x8 kf[4];
#pragma unroll
    for (int mi = 0; mi < 4; ++mi) {
        int px = mi * 16 + lr;
        int dy = px >> 3, dx = px & 7;
        int yg = wy * 8 + dy, xg = wx * 8 + dx;
        float gx = -1.0f + xg * (2.0f / 127.0f) + ((float)dx - 3.5f) * (2.0f / 127.0f) * sbv.x + sbv.z;
        float gy = -1.0f + yg * (2.0f / 127.0f) + ((float)dy - 3.5f) * (2.0f / 127.0f) * sbv.y + sbv.w;
        float fx = (gx + 1.0f) * 0.5f * 127.0f;
        float fy = (gy + 1.0f) * 0.5f * 127.0f;
        float x0f = floorf(fx), y0f = floorf(fy);
        float wx1 = fx - x0f, wy1 = fy - y0f;
        int ix0 = (int)x0f, iy0 = (int)y0f;
        int ix1 = ix0 + 1, iy1 = iy0 + 1;
        float w00 = (1.0f - wx1) * (1.0f - wy1);
        float w10 = wx1 * (1.0f - wy1);
        float w01 = (1.0f - wx1) * wy1;
        float w11 = wx1 * wy1;
        bool vX0 = (ix0 >= 0) && (ix0 < IW), vX1 = (ix1 >= 0) && (ix1 < IW);
        bool vY0 = (iy0 >= 0) && (iy0 < IH), vY1 = (iy1 >= 0) && (iy1 < IH);
        if (!(vX0 && vY0)) w00 = 0.f;
        if (!(vX1 && vY0)) w10 = 0.f;
        if (!(vX0 && vY1)) w01 = 0.f;
        if (!(vX1 && vY1)) w11 = 0.f;
        int cx0 = min(max(ix0, 0), IW - 1), cx1 = min(max(ix1, 0), IW - 1);
        int cy0 = min(max(iy0, 0), IH - 1), cy1 = min(max(iy1, 0), IH - 1);
        size_t r00 = ((size_t)p * NPIX + cy0 * IW + cx0) * HDIM + lg * 8;
        size_t r10 = ((size_t)p * NPIX + cy0 * IW + cx1) * HDIM + lg * 8;
        size_t r01 = ((size_t)p * NPIX + cy1 * IW + cx0) * HDIM + lg * 8;
        size_t r11 = ((size_t)p * NPIX + cy1 * IW + cx1) * HDIM + lg * 8;
        u16x8 k00 = *(const u16x8*)&kb[r00], k10 = *(const u16x8*)&kb[r10];
        u16x8 k01 = *(const u16x8*)&kb[r01], k11 = *(const u16x8*)&kb[r11];
        u16x8 v00 = *(const u16x8*)&vb[r00], v10 = *(const u16x8*)&vb[r10];
        u16x8 v01 = *(const u16x8*)&vb[r01], v11 = *(const u16x8*)&vb[r11];
#pragma unroll
        for (int c = 0; c < 8; ++c) {
            float kvv = w00 * bf2f(k00[c]) + w10 * bf2f(k10[c]) +
                        w01 * bf2f(k01[c]) + w11 * bf2f(k11[c]);
            float vvv = w00 * bf2f(v00[c]) + w10 * bf2f(v10[c]) +
                        w01 * bf2f(v01[c]) + w11 * bf2f(v11[c]);
            kf[mi][c] = (short)f2bf(kvv);
            Vl[wv][px][lg * 8 + c] = f2bf(vvv);
        }
    }

    f32x4 acc[4][4];
#pragma unroll
    for (int tk = 0; tk < 4; ++tk)
#pragma unroll
        for (int tq = 0; tq < 4; ++tq) acc[tk][tq] = (f32x4){0.f, 0.f, 0.f, 0.f};
#pragma unroll
    for (int tk = 0; tk < 4; ++tk)
#pragma unroll
        for (int tq = 0; tq < 4; ++tq)
            acc[tk][tq] = __builtin_amdgcn_mfma_f32_16x16x32_bf16(kf[tk], qf[tq], acc[tk][tq], 0, 0, 0);

    __syncthreads();

    const float scale = 0.17677669529663688f;
    int qh[4], qwv[4];
#pragma unroll
    for (int tq = 0; tq < 4; ++tq) { int q = tq * 16 + lr; qh[tq] = q >> 3; qwv[tq] = q & 7; }
    float mx[4] = {-1e30f, -1e30f, -1e30f, -1e30f};
#pragma unroll
    for (int tk = 0; tk < 4; ++tk)
#pragma unroll
        for (int r = 0; r < 4; ++r) {
            int key = tk * 16 + lg * 4 + r;
            int kh = key >> 3, kw = key & 7;
#pragma unroll
            for (int tq = 0; tq < 4; ++tq) {
                float v = acc[tk][tq][r] * scale + rel_s[(qh[tq] - kh + 7) * 15 + (qwv[tq] - kw + 7)];
                acc[tk][tq][r] = v;
                mx[tq] = fmaxf(mx[tq], v);
            }
        }
#pragma unroll
    for (int tq = 0; tq < 4; ++tq) {
        mx[tq] = fmaxf(mx[tq], __shfl_xor(mx[tq], 16));
        mx[tq] = fmaxf(mx[tq], __shfl_xor(mx[tq], 32));
    }
    float sm[4] = {0.f, 0.f, 0.f, 0.f};
#pragma unroll
    for (int tk = 0; tk < 4; ++tk)
#pragma unroll
        for (int tq = 0; tq < 4; ++tq)
#pragma unroll
            for (int r = 0; r < 4; ++r) {
                float e = __expf(acc[tk][tq][r] - mx[tq]);
                acc[tk][tq][r] = e;
                sm[tq] += e;
            }
    float inv[4];
#pragma unroll
    for (int tq = 0; tq < 4; ++tq) {
        float s = sm[tq];
        s += __shfl_xor(s, 16);
        s += __shfl_xor(s, 32);
        inv[tq] = 1.0f / s;
    }
#pragma unroll
    for (int tq = 0; tq < 4; ++tq)
#pragma unroll
        for (int tk = 0; tk < 4; ++tk) {
            u16x4 pk = { f2bf(acc[tk][tq][0] * inv[tq]), f2bf(acc[tk][tq][1] * inv[tq]),
                         f2bf(acc[tk][tq][2] * inv[tq]), f2bf(acc[tk][tq][3] * inv[tq]) };
            *(u16x4*)&Pl[wv][tq * 16 + lr][tk * 16 + lg * 4] = pk;
        }

    __syncthreads();

    f32x4 o[4][2];
#pragma unroll
    for (int mq = 0; mq < 4; ++mq)
#pragma unroll
        for (int nd = 0; nd < 2; ++nd) o[mq][nd] = (f32x4){0.f, 0.f, 0.f, 0.f};
#pragma unroll
    for (int ks = 0; ks < 2; ++ks) {
        bf16x8 Af[4];
#pragma unroll
        for (int mq = 0; mq < 4; ++mq) {
            u16x4 lo = *(const u16x4*)&Pl[wv][mq * 16 + lr][ks * 32 + lg * 8];
            u16x4 hi = *(const u16x4*)&Pl[wv][mq * 16 + lr][ks * 32 + lg * 8 + 4];
#pragma unroll
            for (int c = 0; c < 4; ++c) { Af[mq][c] = (short)lo[c]; Af[mq][c + 4] = (short)hi[c]; }
        }
        bf16x8 Bf[2];
#pragma unroll
        for (int nd = 0; nd < 2; ++nd)
#pragma unroll
            for (int j = 0; j < 8; ++j)
                Bf[nd][j] = (short)Vl[wv][ks * 32 + lg * 8 + j][nd * 16 + lr];
#pragma unroll
        for (int mq = 0; mq < 4; ++mq)
#pragma unroll
            for (int nd = 0; nd < 2; ++nd)
                o[mq][nd] = __builtin_amdgcn_mfma_f32_16x16x32_bf16(Af[mq], Bf[nd], o[mq][nd], 0, 0, 0);
    }

#pragma unroll
    for (int mq = 0; mq < 4; ++mq)
#pragma unroll
        for (int nd = 0; nd < 2; ++nd)
#pragma unroll
            for (int r = 0; r < 4; ++r) {
                int q = mq * 16 + lg * 4 + r;
                int pix = (wy * 8 + (q >> 3)) * IW + wx * 8 + (q & 7);
                qatt[((size_t)b * NPIX + pix) * CCH + head * HDIM + nd * 16 + lr] = f2bf(o[mq][nd][r]);
            }
}

// ---------------------------------------------------------------------------
// K5: projection via bf16 MFMA: out = proj_w(bf16) @ att + proj_b.
// ---------------------------------------------------------------------------
__global__ __launch_bounds__(256) void k5_mfma(const unsigned short* __restrict__ att,
                                               const unsigned short* __restrict__ wp,
                                               const float* __restrict__ proj_b,
                                               float* __restrict__ out) {
    constexpr int BN = 128, KC = 64, KCP = 72;
    __shared__ unsigned short Ws[CCH][KCP];
    __shared__ unsigned short Xt[BN][KCP];
    int px0 = blockIdx.x * BN;
    int b = blockIdx.y;
    int tid = threadIdx.x;
    int wv = tid >> 6, lane = tid & 63, lr = lane & 15, lg = lane >> 4;

    f32x4 acc[3][8];
#pragma unroll
    for (int i = 0; i < 3; ++i)
#pragma unroll
        for (int j = 0; j < 8; ++j) acc[i][j] = (f32x4){0.f, 0.f, 0.f, 0.f};

    int spx = tid & 127, skg = tid >> 7;

    for (int k0 = 0; k0 < CCH; k0 += KC) {
#pragma unroll
        for (int i = 0; i < 6; ++i) {
            int u = tid + 256 * i;
            int o = u >> 3, kb8 = u & 7;
            *(u16x8*)&Ws[o][kb8 * 8] = *(const u16x8*)&wp[(size_t)o * CCH + k0 + kb8 * 8];
        }
        {
            const unsigned short* arow = &att[((size_t)b * NPIX + px0 + spx) * CCH + k0 + skg * 32];
#pragma unroll
            for (int j8 = 0; j8 < 4; ++j8)
                *(u16x8*)&Xt[spx][skg * 32 + j8 * 8] = *(const u16x8*)&arow[j8 * 8];
        }
        __syncthreads();
#pragma unroll
        for (int kk = 0; kk < KC; kk += 32) {
            bf16x8 af[3], bfr[8];
#pragma unroll
            for (int i = 0; i < 3; ++i)
                af[i] = *(const bf16x8*)&Ws[wv * 48 + i * 16 + lr][kk + lg * 8];
#pragma unroll
            for (int j = 0; j < 8; ++j)
                bfr[j] = *(const bf16x8*)&Xt[j * 16 + lr][kk + lg * 8];
#pragma unroll
            for (int i = 0; i < 3; ++i)
#pragma unroll
                for (int j = 0; j < 8; ++j)
                    acc[i][j] = __builtin_amdgcn_mfma_f32_16x16x32_bf16(af[i], bfr[j], acc[i][j], 0, 0, 0);
        }
        __syncthreads();
    }

#pragma unroll
    for (int i = 0; i < 3; ++i) {
        int och = wv * 48 + i * 16 + lg * 4;
#pragma unroll
        for (int r = 0; r < 4; ++r) {
            float bias = proj_b[och + r];
            size_t base = (size_t)(b * CCH + och + r) * NPIX + px0 + lr;
#pragma unroll
            for (int j = 0; j < 8; ++j)
                out[base + j * 16] = acc[i][j][r] + bias;
        }
    }
}

// ---------------------------------------------------------------------------
extern "C" void kernel_launch(void* const* d_in, const int* in_sizes, int n_in,
                              void* d_out, int out_size, void* d_ws, size_t ws_size,
                              hipStream_t stream) {
    const float* x = (const float*)d_in[0];
    const float* var = (const float*)d_in[1];
    const float* qkv_w = (const float*)d_in[2];
    const float* qkv_b = (const float*)d_in[3];
    const float* bias_w = (const float*)d_in[4];
    const float* bias_b = (const float*)d_in[5];
    const float* scale_w = (const float*)d_in[6];
    const float* scale_b = (const float*)d_in[7];
    const float* proj_w = (const float*)d_in[8];
    const float* proj_b = (const float*)d_in[9];
    const float* rel_table = (const float*)d_in[10];
    float* out = (float*)d_out;

    char* ws = (char*)d_ws;
    float* pooled = (float*)ws;
    float* sb = (float*)(ws + 1572864ull);
    unsigned short* wbf = (unsigned short*)ws;            // overlaps pooled (k2 done first)
    unsigned short* wq_bf = wbf;
    unsigned short* wp_bf = wbf + 110592;
    const size_t elemQ = (size_t)BB * CCH * NPIX;
    unsigned short* q = (unsigned short*)(ws + 1769472ull);
    unsigned short* k = q + elemQ;
    unsigned short* v = k + elemQ;
    unsigned short* xt = v + elemQ;

    size_t need_base = 1769472ull + 3ull * elemQ * 2;
    size_t need_fast = 1769472ull + 4ull * elemQ * 2;
    if (ws_size < need_base) return;
    bool fast = ws_size >= need_fast;

    k1_pool<<<dim3(BB * CCH), dim3(256), 0, stream>>>(x, var, pooled);
    k2_sb<<<dim3(BB * NWIN), dim3(64), 0, stream>>>(pooled, bias_w, bias_b, scale_w, scale_b, sb);
    kw_conv<<<dim3(144), dim3(256), 0, stream>>>(qkv_w, proj_w, wbf);
    if (fast) {
        k0_xpose<<<dim3(NPIX / 64, BB), dim3(256), 0, stream>>>(x, xt);
        k3_mfma<true><<<dim3(NPIX / 128, 3, BB), dim3(256), 0, stream>>>(x, xt, wq_bf, qkv_b, q, k, v);
    } else {
        k3_mfma<false><<<dim3(NPIX / 128, 3, BB), dim3(256), 0, stream>>>(x, xt, wq_bf, qkv_b, q, k, v);
    }
    k4_attn<<<dim3(NWIN / 4, NH, BB), dim3(256), 0, stream>>>(q, k, v, sb, rel_table);
    k5_mfma<<<dim3(NPIX / 128, BB), dim3(256), 0, stream>>>(q, wp_bf, proj_b, out);
}

// Round 10
// 289.383 us; speedup vs baseline: 1.2979x; 1.1643x over previous
//
#include <hip/hip_runtime.h>
#include <hip/hip_bf16.h>
#include <math.h>

constexpr int BB = 8, CCH = 192, IH = 128, IW = 128;
constexpr int WSZ = 8;
constexpr int NWIN = 256;
constexpr int NH = 6, HDIM = 32;
constexpr int NPIX = IH * IW;
constexpr int TOPK = 13107;

typedef __attribute__((ext_vector_type(8))) short bf16x8;
typedef __attribute__((ext_vector_type(4))) float f32x4;
typedef __attribute__((ext_vector_type(4))) unsigned short u16x4;
typedef __attribute__((ext_vector_type(8))) unsigned short u16x8;

__device__ __forceinline__ unsigned short f2bf(float f) {
    __hip_bfloat16 h = __float2bfloat16(f);
    return __builtin_bit_cast(unsigned short, h);
}
__device__ __forceinline__ float bf2f(unsigned short u) {
    return __uint_as_float((unsigned)u << 16);
}
__device__ __forceinline__ unsigned monot(float f) {
    unsigned u = __float_as_uint(f);
    return (u & 0x80000000u) ? ~u : (u | 0x80000000u);
}

// ---------------------------------------------------------------------------
// K1: per (b,c) row: exact top-k threshold on var (stable ties like lax.top_k),
//     masked 8x8 avg-pool + leaky_relu -> pooled (b, c, 16, 16).
//     512 threads/row; 12-bit hist (2 copies); fused provisional-pool+collect
//     sweep; exact candidate rank + tiny fixup.
// ---------------------------------------------------------------------------
__global__ __launch_bounds__(512) void k1_pool(const float* __restrict__ x,
                                               const float* __restrict__ var,
                                               float* __restrict__ pooled) {
    int row = blockIdx.x;
    const float4* vrow4 = (const float4*)(var + (size_t)row * NPIX);
    const float4* xrow4 = (const float4*)(x + (size_t)row * NPIX);
    const float* xrow = x + (size_t)row * NPIX;
    int tid = threadIdx.x;
    int wv = tid >> 6, lane = tid & 63;

    constexpr int CAP = 320;
    __shared__ unsigned hist2k[2][4096];      // 32 KB, copies by lane&1
    __shared__ unsigned hist256[256];         // fallback refinement
    __shared__ unsigned wtot[8];
    __shared__ unsigned s_prefix, s_rem, s_cnt, s_thr, s_need;
    __shared__ unsigned candKey[CAP], candIdx[CAP];
    __shared__ unsigned cand_cnt, eq_cnt;
    __shared__ unsigned eq_idx[64];
    __shared__ float pooled_s[256];

    for (int i = tid; i < 2 * 4096; i += 512) ((unsigned*)hist2k)[i] = 0;
    if (tid < 256) pooled_s[tid] = 0.f;
    if (tid == 0) { cand_cnt = 0; eq_cnt = 0; }
    __syncthreads();

    // ---- sweep 1: 12-bit histogram ----
    int hc = lane & 1;
#pragma unroll
    for (int j = 0; j < 8; ++j) {
        float4 v4 = vrow4[tid + 512 * j];
        float vv[4] = {v4.x, v4.y, v4.z, v4.w};
#pragma unroll
        for (int c = 0; c < 4; ++c)
            atomicAdd(&hist2k[hc][monot(vv[c]) >> 20], 1u);
    }
    __syncthreads();

    // ---- scan 4096 buckets: thread owns [8*tid, 8*tid+7] ----
    {
        unsigned h8[8]; unsigned tsum = 0;
#pragma unroll
        for (int i = 0; i < 8; ++i) {
            h8[i] = hist2k[0][tid * 8 + i] + hist2k[1][tid * 8 + i];
            tsum += h8[i];
        }
        unsigned s = tsum;                      // inclusive suffix within wave
#pragma unroll
        for (int off = 1; off < 64; off <<= 1) {
            unsigned t = __shfl(s, lane + off);
            if (lane + off < 64) s += t;
        }
        if (lane == 0) wtot[wv] = s;
        __syncthreads();
        unsigned crossTot = 0;
        for (int w = wv + 1; w < 8; ++w) crossTot += wtot[w];
        unsigned above = crossTot + (s - tsum);
        if (above < TOPK && above + tsum >= TOPK) {
            unsigned cum = above;
            for (int i = 7; i >= 0; --i) {
                if (cum < TOPK && cum + h8[i] >= TOPK) {
                    s_prefix = (unsigned)(tid * 8 + i);
                    s_rem = TOPK - cum;
                    s_cnt = h8[i];
                }
                cum += h8[i];
            }
        }
    }
    __syncthreads();

    unsigned prefix = s_prefix, rem2 = s_rem, cnt = s_cnt;
    int prefbits = 12;

    // ---- fallback refinement (normally 0 iterations) ----
    while (cnt > CAP && prefbits < 32) {
        int nb = (32 - prefbits >= 8) ? 8 : (32 - prefbits);
        int nbuck = 1 << nb;
        __syncthreads();
        for (int i = tid; i < nbuck; i += 512) hist256[i] = 0;
        __syncthreads();
        int shift = 32 - prefbits - nb;
#pragma unroll
        for (int j = 0; j < 8; ++j) {
            float4 v4 = vrow4[tid + 512 * j];
            float vv[4] = {v4.x, v4.y, v4.z, v4.w};
#pragma unroll
            for (int c = 0; c < 4; ++c) {
                unsigned mm = monot(vv[c]);
                if ((mm >> (nb + shift)) == prefix)
                    atomicAdd(&hist256[(mm >> shift) & (nbuck - 1)], 1u);
            }
        }
        __syncthreads();
        if (wv == 0) {
            int bpl = nbuck > 64 ? nbuck / 64 : 1;
            int nlanes = nbuck / bpl;
            unsigned hh[4] = {0, 0, 0, 0};
            unsigned lsum = 0;
#pragma unroll
            for (int i = 0; i < 4; ++i) {
                if (i < bpl && lane < nlanes) hh[i] = hist256[lane * bpl + i];
                lsum += hh[i];
            }
            unsigned s = lsum;
#pragma unroll
            for (int off = 1; off < 64; off <<= 1) {
                unsigned t = __shfl(s, lane + off);
                if (lane + off < 64) s += t;
            }
            unsigned above = s - lsum;
            if (lane < nlanes && above < rem2 && above + lsum >= rem2) {
                unsigned cum = above;
                for (int i = bpl - 1; i >= 0; --i) {
                    if (cum < rem2 && cum + hh[i] >= rem2) {
                        s_prefix = (prefix << nb) | (unsigned)(lane * bpl + i);
                        s_rem = rem2 - cum;
                        s_cnt = hh[i];
                    }
                    cum += hh[i];
                }
            }
        }
        __syncthreads();
        prefix = s_prefix; rem2 = s_rem; cnt = s_cnt;
        prefbits += nb;
    }

    int pshift = 32 - prefbits;   // note: prefbits==32 -> pshift 0 (degenerate, cnt>CAP only)

    // ---- sweep 2 (fused): provisional pooling + candidate collection ----
    // pixel for (tid, j, c) = 4*tid + 2048*j + c ; y = 16j + (tid>>5)
    // window: wy = 2j + (tid>>8), wx = (tid>>1)&15
#pragma unroll
    for (int j = 0; j < 8; ++j) {
        float4 v4 = vrow4[tid + 512 * j];
        float4 x4 = xrow4[tid + 512 * j];
        float vv[4] = {v4.x, v4.y, v4.z, v4.w};
        float xv[4] = {x4.x, x4.y, x4.z, x4.w};
        float part = 0.f;
#pragma unroll
        for (int c = 0; c < 4; ++c) {
            unsigned mm = monot(vv[c]);
            unsigned g = (pshift == 0) ? mm : (mm >> pshift);
            float mult = (g > prefix) ? 1.0f : 0.6f;
            if (g == prefix) {
                unsigned pos = atomicAdd(&cand_cnt, 1u);
                if (pos < CAP) {
                    candKey[pos] = mm;
                    candIdx[pos] = (unsigned)(4 * tid + 2048 * j + c);
                }
            }
            part += xv[c] * mult;
        }
        part += __shfl_xor(part, 1);
        part += __shfl_xor(part, 32);
        if ((lane & 1) == 0 && lane < 32)
            atomicAdd(&pooled_s[(2 * j + (tid >> 8)) * 16 + ((tid >> 1) & 15)], part);
    }
    __syncthreads();

    // ---- exact threshold among candidates (rank via LDS broadcast) ----
    int cc = (int)min(cand_cnt, (unsigned)CAP);
    for (int ci = tid; ci < cc; ci += 512) {
        unsigned my = candKey[ci];
        unsigned kgt = 0, keq = 0;
        for (int e = 0; e < cc; ++e) {
            unsigned o = candKey[e];
            kgt += (o > my);
            keq += (o == my);
        }
        if (kgt < rem2 && kgt + keq >= rem2) {
            s_thr = my;
            s_need = rem2 - kgt;
        }
    }
    __syncthreads();
    unsigned thr = s_thr, need_eq = s_need;
    for (int ci = tid; ci < cc; ci += 512)
        if (candKey[ci] == thr) {
            unsigned pos = atomicAdd(&eq_cnt, 1u);
            if (pos < 64) eq_idx[pos] = candIdx[ci];
        }
    __syncthreads();
    int ecnt = (int)min(eq_cnt, 64u);
    if (tid == 0) {
        for (int a = 1; a < ecnt; ++a) {
            unsigned key = eq_idx[a]; int q = a - 1;
            while (q >= 0 && eq_idx[q] > key) { eq_idx[q + 1] = eq_idx[q]; --q; }
            eq_idx[q + 1] = key;
        }
    }
    __syncthreads();

    // ---- fixup: in-set candidates were pooled at 0.6 -> add 0.4*x ----
    for (int ci = tid; ci < cc; ci += 512) {
        unsigned key = candKey[ci], idx = candIdx[ci];
        bool inset;
        if (key > thr) inset = true;
        else if (key < thr) inset = false;
        else {
            unsigned rank = 0;
            for (int e = 0; e < ecnt; ++e) rank += (eq_idx[e] < idx);
            inset = (rank < need_eq);
        }
        if (inset) {
            int y = (int)(idx >> 7), xx = (int)(idx & 127);
            atomicAdd(&pooled_s[(y >> 3) * 16 + (xx >> 3)], 0.4f * xrow[idx]);
        }
    }
    __syncthreads();

    if (tid < 256) {
        float s = pooled_s[tid] * (1.0f / 64.0f);
        float pv = s > 0.f ? s : 0.01f * s;
        pooled[(size_t)row * NWIN + tid] = pv;
    }
}

// ---------------------------------------------------------------------------
// K2: per (b, window): dots with bias_w/scale_w -> sb[p][win] = {sx,sy,bx/16,by/16}
// ---------------------------------------------------------------------------
__global__ __launch_bounds__(64) void k2_sb(const float* __restrict__ pooled,
                                            const float* __restrict__ bias_w,
                                            const float* __restrict__ bias_b,
                                            const float* __restrict__ scale_w,
                                            const float* __restrict__ scale_b,
                                            float* __restrict__ sb) {
    int blk = blockIdx.x;
    int b = blk / NWIN, w = blk % NWIN;
    int tid = threadIdx.x;
    __shared__ float pcol[CCH];
    __shared__ float res[24];
    for (int c = tid; c < CCH; c += 64) pcol[c] = pooled[(size_t)(b * CCH + c) * NWIN + w];
    __syncthreads();
    if (tid < 24) {
        bool isScale = tid >= 12;
        int o = isScale ? tid - 12 : tid;
        const float* Wt = isScale ? scale_w : bias_w;
        float acc = 0.f;
        for (int c = 0; c < CCH; ++c) acc += Wt[o * CCH + c] * pcol[c];
        acc += (isScale ? scale_b[o] : bias_b[o]);
        if (!isScale) acc *= (1.0f / 16.0f);
        res[tid] = acc;
    }
    __syncthreads();
    if (tid < NH) {
        int p = b * NH + tid;
        float4 v;
        v.x = res[12 + 2 * tid];
        v.y = res[12 + 2 * tid + 1];
        v.z = res[2 * tid];
        v.w = res[2 * tid + 1];
        ((float4*)sb)[(size_t)p * NWIN + w] = v;
    }
}

// ---------------------------------------------------------------------------
// KW: convert qkv_w (110592 f32) + proj_w (36864 f32) -> bf16, concatenated.
// ---------------------------------------------------------------------------
__global__ __launch_bounds__(256) void kw_conv(const float* __restrict__ qkv_w,
                                               const float* __restrict__ proj_w,
                                               unsigned short* __restrict__ wbf) {
    int i4 = blockIdx.x * 256 + threadIdx.x;
    float4 v = (i4 < 27648) ? ((const float4*)qkv_w)[i4]
                            : ((const float4*)proj_w)[i4 - 27648];
    u16x4 pk = { f2bf(v.x), f2bf(v.y), f2bf(v.z), f2bf(v.w) };
    ((u16x4*)wbf)[i4] = pk;
}

// ---------------------------------------------------------------------------
// K0X: transpose x (b, c, px) f32 -> xt (b, px, c) bf16, LDS-tiled.
// ---------------------------------------------------------------------------
__global__ __launch_bounds__(256) void k0_xpose(const float* __restrict__ x,
                                                unsigned short* __restrict__ xt) {
    __shared__ unsigned short T[64][200];
    int px0 = blockIdx.x * 64;
    int b = blockIdx.y;
    int tid = threadIdx.x;
    int px = tid & 63, cg = tid >> 6;

#pragma unroll
    for (int j8 = 0; j8 < 6; ++j8) {
        u16x8 pk;
#pragma unroll
        for (int j = 0; j < 8; ++j)
            pk[j] = f2bf(x[(size_t)(b * CCH + cg * 48 + j8 * 8 + j) * NPIX + px0 + px]);
        *(u16x8*)&T[px][cg * 48 + j8 * 8] = pk;
    }
    __syncthreads();
#pragma unroll
    for (int i = 0; i < 6; ++i) {
        int u = tid + 256 * i;
        int p2 = u / 24, cb = u % 24;
        *(u16x8*)&xt[((size_t)(b * NPIX) + px0 + p2) * CCH + cb * 8] = *(const u16x8*)&T[p2][cb * 8];
    }
}

// ---------------------------------------------------------------------------
// K3: qkv 1x1 conv via bf16 MFMA, channel-last outputs:
//     q: (b, px, 192)   k/v: (b*NH+head, px, 32)
// ---------------------------------------------------------------------------
template <bool FAST>
__global__ __launch_bounds__(256) void k3_mfma(const float* __restrict__ x,
                                               const unsigned short* __restrict__ xt,
                                               const unsigned short* __restrict__ wq,
                                               const float* __restrict__ qkv_b,
                                               unsigned short* __restrict__ qb,
                                               unsigned short* __restrict__ kb,
                                               unsigned short* __restrict__ vb) {
    constexpr int BN = 128, KC = 64, KCP = 72;
    __shared__ unsigned short Ws[CCH][KCP];
    __shared__ unsigned short Xt[BN][KCP];
    int px0 = blockIdx.x * BN;
    int t = blockIdx.y, b = blockIdx.z;
    int o0 = t * CCH;
    int tid = threadIdx.x;
    int wv = tid >> 6, lane = tid & 63, lr = lane & 15, lg = lane >> 4;

    f32x4 acc[3][8];
#pragma unroll
    for (int i = 0; i < 3; ++i)
#pragma unroll
        for (int j = 0; j < 8; ++j) acc[i][j] = (f32x4){0.f, 0.f, 0.f, 0.f};

    int spx = tid & 127, skg = tid >> 7;

    for (int k0 = 0; k0 < CCH; k0 += KC) {
#pragma unroll
        for (int i = 0; i < 6; ++i) {
            int u = tid + 256 * i;
            int o = u >> 3, kb8 = u & 7;
            *(u16x8*)&Ws[o][kb8 * 8] = *(const u16x8*)&wq[(size_t)(o0 + o) * CCH + k0 + kb8 * 8];
        }
        if (FAST) {
#pragma unroll
            for (int i = 0; i < 4; ++i) {
                int u = tid + 256 * i;
                int px = u >> 3, kb8 = u & 7;
                *(u16x8*)&Xt[px][kb8 * 8] =
                    *(const u16x8*)&xt[((size_t)(b * NPIX) + px0 + px) * CCH + k0 + kb8 * 8];
            }
        } else {
            const float* xcol = &x[(size_t)(b * CCH + k0 + skg * 32) * NPIX + px0 + spx];
#pragma unroll
            for (int j8 = 0; j8 < 4; ++j8) {
                u16x8 pk;
#pragma unroll
                for (int j = 0; j < 8; ++j) pk[j] = f2bf(xcol[(size_t)(j8 * 8 + j) * NPIX]);
                *(u16x8*)&Xt[spx][skg * 32 + j8 * 8] = pk;
            }
        }
        __syncthreads();
#pragma unroll
        for (int kk = 0; kk < KC; kk += 32) {
            bf16x8 af[3], bfr[8];
#pragma unroll
            for (int i = 0; i < 3; ++i)
                af[i] = *(const bf16x8*)&Ws[wv * 48 + i * 16 + lr][kk + lg * 8];
#pragma unroll
            for (int j = 0; j < 8; ++j)
                bfr[j] = *(const bf16x8*)&Xt[j * 16 + lr][kk + lg * 8];
#pragma unroll
            for (int i = 0; i < 3; ++i)
#pragma unroll
                for (int j = 0; j < 8; ++j)
                    acc[i][j] = __builtin_amdgcn_mfma_f32_16x16x32_bf16(af[i], bfr[j], acc[i][j], 0, 0, 0);
        }
        __syncthreads();
    }

#pragma unroll
    for (int i = 0; i < 3; ++i) {
        int och = wv * 48 + i * 16 + lg * 4;
        float b0 = qkv_b[o0 + och], b1 = qkv_b[o0 + och + 1];
        float b2 = qkv_b[o0 + och + 2], b3 = qkv_b[o0 + och + 3];
#pragma unroll
        for (int j = 0; j < 8; ++j) {
            int px = px0 + lr + j * 16;
            u16x4 pk = { f2bf(acc[i][j][0] + b0), f2bf(acc[i][j][1] + b1),
                         f2bf(acc[i][j][2] + b2), f2bf(acc[i][j][3] + b3) };
            if (t == 0) {
                *(u16x4*)&qb[((size_t)b * NPIX + px) * CCH + och] = pk;
            } else {
                int head = och >> 5, d = och & 31;
                unsigned short* dst = (t == 1) ? kb : vb;
                *(u16x4*)&dst[(((size_t)(b * NH + head)) * NPIX + px) * HDIM + d] = pk;
            }
        }
    }
}

// ---------------------------------------------------------------------------
// K4: wave-per-window MFMA attention. S^T = K_samp . Q^T, softmax in-register,
//     PV via MFMA with P,V in LDS. Writes att (bf16, channel-last) into qb.
// ---------------------------------------------------------------------------
__global__ __launch_bounds__(256) void k4_attn(unsigned short* __restrict__ qatt,
                                               const unsigned short* __restrict__ kb,
                                               const unsigned short* __restrict__ vb,
                                               const float* __restrict__ sb,
                                               const float* __restrict__ rel_table) {
    int tid = threadIdx.x;
    int wv = tid >> 6, lane = tid & 63, lr = lane & 15, lg = lane >> 4;
    int head = blockIdx.y, b = blockIdx.z;
    int win = blockIdx.x * 4 + wv;
    int wy = win >> 4, wx = win & 15;
    int p = b * NH + head;

    __shared__ float rel_s[225];
    __shared__ unsigned short Vl[4][64][33];
    __shared__ unsigned short Pl[4][64][68];

    if (tid < 225) rel_s[tid] = rel_table[tid * NH + head];

    bf16x8 qf[4];
#pragma unroll
    for (int tq = 0; tq < 4; ++tq) {
        int q = tq * 16 + lr;
        int pix = (wy * 8 + (q >> 3)) * IW + wx * 8 + (q & 7);
        qf[tq] = *(const bf16x8*)&qatt[((size_t)b * NPIX + pix) * CCH + head * HDIM + lg * 8];
    }

    float4 sbv = ((const float4*)sb)[(size_t)p * NWIN + win];
    bf16x8 kf[4];
#pragma unroll
    for (int mi = 0; mi < 4; ++mi) {
        int px = mi * 16 + lr;
        int dy = px >> 3, dx = px & 7;
        int yg = wy * 8 + dy, xg = wx * 8 + dx;
        float gx = -1.0f + xg * (2.0f / 127.0f) + ((float)dx - 3.5f) * (2.0f / 127.0f) * sbv.x + sbv.z;
        float gy = -1.0f + yg * (2.0f / 127.0f) + ((float)dy - 3.5f) * (2.0f / 127.0f) * sbv.y + sbv.w;
        float fx = (gx + 1.0f) * 0.5f * 127.0f;
        float fy = (gy + 1.0f) * 0.5f * 127.0f;
        float x0f = floorf(fx), y0f = floorf(fy);
        float wx1 = fx - x0f, wy1 = fy - y0f;
        int ix0 = (int)x0f, iy0 = (int)y0f;
        int ix1 = ix0 + 1, iy1 = iy0 + 1;
        float w00 = (1.0f - wx1) * (1.0f - wy1);
        float w10 = wx1 * (1.0f - wy1);
        float w01 = (1.0f - wx1) * wy1;
        float w11 = wx1 * wy1;
        bool vX0 = (ix0 >= 0) && (ix0 < IW), vX1 = (ix1 >= 0) && (ix1 < IW);
        bool vY0 = (iy0 >= 0) && (iy0 < IH), vY1 = (iy1 >= 0) && (iy1 < IH);
        if (!(vX0 && vY0)) w00 = 0.f;
        if (!(vX1 && vY0)) w10 = 0.f;
        if (!(vX0 && vY1)) w01 = 0.f;
        if (!(vX1 && vY1)) w11 = 0.f;
        int cx0 = min(max(ix0, 0), IW - 1), cx1 = min(max(ix1, 0), IW - 1);
        int cy0 = min(max(iy0, 0), IH - 1), cy1 = min(max(iy1, 0), IH - 1);
        size_t r00 = ((size_t)p * NPIX + cy0 * IW + cx0) * HDIM + lg * 8;
        size_t r10 = ((size_t)p * NPIX + cy0 * IW + cx1) * HDIM + lg * 8;
        size_t r01 = ((size_t)p * NPIX + cy1 * IW + cx0) * HDIM + lg * 8;
        size_t r11 = ((size_t)p * NPIX + cy1 * IW + cx1) * HDIM + lg * 8;
        u16x8 k00 = *(const u16x8*)&kb[r00], k10 = *(const u16x8*)&kb[r10];
        u16x8 k01 = *(const u16x8*)&kb[r01], k11 = *(const u16x8*)&kb[r11];
        u16x8 v00 = *(const u16x8*)&vb[r00], v10 = *(const u16x8*)&vb[r10];
        u16x8 v01 = *(const u16x8*)&vb[r01], v11 = *(const u16x8*)&vb[r11];
#pragma unroll
        for (int c = 0; c < 8; ++c) {
            float kvv = w00 * bf2f(k00[c]) + w10 * bf2f(k10[c]) +
                        w01 * bf2f(k01[c]) + w11 * bf2f(k11[c]);
            float vvv = w00 * bf2f(v00[c]) + w10 * bf2f(v10[c]) +
                        w01 * bf2f(v01[c]) + w11 * bf2f(v11[c]);
            kf[mi][c] = (short)f2bf(kvv);
            Vl[wv][px][lg * 8 + c] = f2bf(vvv);
        }
    }

    f32x4 acc[4][4];
#pragma unroll
    for (int tk = 0; tk < 4; ++tk)
#pragma unroll
        for (int tq = 0; tq < 4; ++tq) acc[tk][tq] = (f32x4){0.f, 0.f, 0.f, 0.f};
#pragma unroll
    for (int tk = 0; tk < 4; ++tk)
#pragma unroll
        for (int tq = 0; tq < 4; ++tq)
            acc[tk][tq] = __builtin_amdgcn_mfma_f32_16x16x32_bf16(kf[tk], qf[tq], acc[tk][tq], 0, 0, 0);

    __syncthreads();

    const float scale = 0.17677669529663688f;
    int qh[4], qwv[4];
#pragma unroll
    for (int tq = 0; tq < 4; ++tq) { int q = tq * 16 + lr; qh[tq] = q >> 3; qwv[tq] = q & 7; }
    float mx[4] = {-1e30f, -1e30f, -1e30f, -1e30f};
#pragma unroll
    for (int tk = 0; tk < 4; ++tk)
#pragma unroll
        for (int r = 0; r < 4; ++r) {
            int key = tk * 16 + lg * 4 + r;
            int kh = key >> 3, kw = key & 7;
#pragma unroll
            for (int tq = 0; tq < 4; ++tq) {
                float v = acc[tk][tq][r] * scale + rel_s[(qh[tq] - kh + 7) * 15 + (qwv[tq] - kw + 7)];
                acc[tk][tq][r] = v;
                mx[tq] = fmaxf(mx[tq], v);
            }
        }
#pragma unroll
    for (int tq = 0; tq < 4; ++tq) {
        mx[tq] = fmaxf(mx[tq], __shfl_xor(mx[tq], 16));
        mx[tq] = fmaxf(mx[tq], __shfl_xor(mx[tq], 32));
    }
    float sm[4] = {0.f, 0.f, 0.f, 0.f};
#pragma unroll
    for (int tk = 0; tk < 4; ++tk)
#pragma unroll
        for (int tq = 0; tq < 4; ++tq)
#pragma unroll
            for (int r = 0; r < 4; ++r) {
                float e = __expf(acc[tk][tq][r] - mx[tq]);
                acc[tk][tq][r] = e;
                sm[tq] += e;
            }
    float inv[4];
#pragma unroll
    for (int tq = 0; tq < 4; ++tq) {
        float s = sm[tq];
        s += __shfl_xor(s, 16);
        s += __shfl_xor(s, 32);
        inv[tq] = 1.0f / s;
    }
#pragma unroll
    for (int tq = 0; tq < 4; ++tq)
#pragma unroll
        for (int tk = 0; tk < 4; ++tk) {
            u16x4 pk = { f2bf(acc[tk][tq][0] * inv[tq]), f2bf(acc[tk][tq][1] * inv[tq]),
                         f2bf(acc[tk][tq][2] * inv[tq]), f2bf(acc[tk][tq][3] * inv[tq]) };
            *(u16x4*)&Pl[wv][tq * 16 + lr][tk * 16 + lg * 4] = pk;
        }

    __syncthreads();

    f32x4 o[4][2];
#pragma unroll
    for (int mq = 0; mq < 4; ++mq)
#pragma unroll
        for (int nd = 0; nd < 2; ++nd) o[mq][nd] = (f32x4){0.f, 0.f, 0.f, 0.f};
#pragma unroll
    for (int ks = 0; ks < 2; ++ks) {
        bf16x8 Af[4];
#pragma unroll
        for (int mq = 0; mq < 4; ++mq) {
            u16x4 lo = *(const u16x4*)&Pl[wv][mq * 16 + lr][ks * 32 + lg * 8];
            u16x4 hi = *(const u16x4*)&Pl[wv][mq * 16 + lr][ks * 32 + lg * 8 + 4];
#pragma unroll
            for (int c = 0; c < 4; ++c) { Af[mq][c] = (short)lo[c]; Af[mq][c + 4] = (short)hi[c]; }
        }
        bf16x8 Bf[2];
#pragma unroll
        for (int nd = 0; nd < 2; ++nd)
#pragma unroll
            for (int j = 0; j < 8; ++j)
                Bf[nd][j] = (short)Vl[wv][ks * 32 + lg * 8 + j][nd * 16 + lr];
#pragma unroll
        for (int mq = 0; mq < 4; ++mq)
#pragma unroll
            for (int nd = 0; nd < 2; ++nd)
                o[mq][nd] = __builtin_amdgcn_mfma_f32_16x16x32_bf16(Af[mq], Bf[nd], o[mq][nd], 0, 0, 0);
    }

#pragma unroll
    for (int mq = 0; mq < 4; ++mq)
#pragma unroll
        for (int nd = 0; nd < 2; ++nd)
#pragma unroll
            for (int r = 0; r < 4; ++r) {
                int q = mq * 16 + lg * 4 + r;
                int pix = (wy * 8 + (q >> 3)) * IW + wx * 8 + (q & 7);
                qatt[((size_t)b * NPIX + pix) * CCH + head * HDIM + nd * 16 + lr] = f2bf(o[mq][nd][r]);
            }
}

// ---------------------------------------------------------------------------
// K5: projection via bf16 MFMA: out = proj_w(bf16) @ att + proj_b.
// ---------------------------------------------------------------------------
__global__ __launch_bounds__(256) void k5_mfma(const unsigned short* __restrict__ att,
                                               const unsigned short* __restrict__ wp,
                                               const float* __restrict__ proj_b,
                                               float* __restrict__ out) {
    constexpr int BN = 128, KC = 64, KCP = 72;
    __shared__ unsigned short Ws[CCH][KCP];
    __shared__ unsigned short Xt[BN][KCP];
    int px0 = blockIdx.x * BN;
    int b = blockIdx.y;
    int tid = threadIdx.x;
    int wv = tid >> 6, lane = tid & 63, lr = lane & 15, lg = lane >> 4;

    f32x4 acc[3][8];
#pragma unroll
    for (int i = 0; i < 3; ++i)
#pragma unroll
        for (int j = 0; j < 8; ++j) acc[i][j] = (f32x4){0.f, 0.f, 0.f, 0.f};

    int spx = tid & 127, skg = tid >> 7;

    for (int k0 = 0; k0 < CCH; k0 += KC) {
#pragma unroll
        for (int i = 0; i < 6; ++i) {
            int u = tid + 256 * i;
            int o = u >> 3, kb8 = u & 7;
            *(u16x8*)&Ws[o][kb8 * 8] = *(const u16x8*)&wp[(size_t)o * CCH + k0 + kb8 * 8];
        }
        {
            const unsigned short* arow = &att[((size_t)b * NPIX + px0 + spx) * CCH + k0 + skg * 32];
#pragma unroll
            for (int j8 = 0; j8 < 4; ++j8)
                *(u16x8*)&Xt[spx][skg * 32 + j8 * 8] = *(const u16x8*)&arow[j8 * 8];
        }
        __syncthreads();
#pragma unroll
        for (int kk = 0; kk < KC; kk += 32) {
            bf16x8 af[3], bfr[8];
#pragma unroll
            for (int i = 0; i < 3; ++i)
                af[i] = *(const bf16x8*)&Ws[wv * 48 + i * 16 + lr][kk + lg * 8];
#pragma unroll
            for (int j = 0; j < 8; ++j)
                bfr[j] = *(const bf16x8*)&Xt[j * 16 + lr][kk + lg * 8];
#pragma unroll
            for (int i = 0; i < 3; ++i)
#pragma unroll
                for (int j = 0; j < 8; ++j)
                    acc[i][j] = __builtin_amdgcn_mfma_f32_16x16x32_bf16(af[i], bfr[j], acc[i][j], 0, 0, 0);
        }
        __syncthreads();
    }

#pragma unroll
    for (int i = 0; i < 3; ++i) {
        int och = wv * 48 + i * 16 + lg * 4;
#pragma unroll
        for (int r = 0; r < 4; ++r) {
            float bias = proj_b[och + r];
            size_t base = (size_t)(b * CCH + och + r) * NPIX + px0 + lr;
#pragma unroll
            for (int j = 0; j < 8; ++j)
                out[base + j * 16] = acc[i][j][r] + bias;
        }
    }
}

// ---------------------------------------------------------------------------
extern "C" void kernel_launch(void* const* d_in, const int* in_sizes, int n_in,
                              void* d_out, int out_size, void* d_ws, size_t ws_size,
                              hipStream_t stream) {
    const float* x = (const float*)d_in[0];
    const float* var = (const float*)d_in[1];
    const float* qkv_w = (const float*)d_in[2];
    const float* qkv_b = (const float*)d_in[3];
    const float* bias_w = (const float*)d_in[4];
    const float* bias_b = (const float*)d_in[5];
    const float* scale_w = (const float*)d_in[6];
    const float* scale_b = (const float*)d_in[7];
    const float* proj_w = (const float*)d_in[8];
    const float* proj_b = (const float*)d_in[9];
    const float* rel_table = (const float*)d_in[10];
    float* out = (float*)d_out;

    char* ws = (char*)d_ws;
    float* pooled = (float*)ws;
    float* sb = (float*)(ws + 1572864ull);
    unsigned short* wbf = (unsigned short*)ws;            // overlaps pooled (k2 done first)
    unsigned short* wq_bf = wbf;
    unsigned short* wp_bf = wbf + 110592;
    const size_t elemQ = (size_t)BB * CCH * NPIX;
    unsigned short* q = (unsigned short*)(ws + 1769472ull);
    unsigned short* k = q + elemQ;
    unsigned short* v = k + elemQ;
    unsigned short* xt = v + elemQ;

    size_t need_base = 1769472ull + 3ull * elemQ * 2;
    size_t need_fast = 1769472ull + 4ull * elemQ * 2;
    if (ws_size < need_base) return;
    bool fast = ws_size >= need_fast;

    k1_pool<<<dim3(BB * CCH), dim3(512), 0, stream>>>(x, var, pooled);
    k2_sb<<<dim3(BB * NWIN), dim3(64), 0, stream>>>(pooled, bias_w, bias_b, scale_w, scale_b, sb);
    kw_conv<<<dim3(144), dim3(256), 0, stream>>>(qkv_w, proj_w, wbf);
    if (fast) {
        k0_xpose<<<dim3(NPIX / 64, BB), dim3(256), 0, stream>>>(x, xt);
        k3_mfma<true><<<dim3(NPIX / 128, 3, BB), dim3(256), 0, stream>>>(x, xt, wq_bf, qkv_b, q, k, v);
    } else {
        k3_mfma<false><<<dim3(NPIX / 128, 3, BB), dim3(256), 0, stream>>>(x, xt, wq_bf, qkv_b, q, k, v);
    }
    k4_attn<<<dim3(NWIN / 4, NH, BB), dim3(256), 0, stream>>>(q, k, v, sb, rel_table);
    k5_mfma<<<dim3(NPIX / 128, BB), dim3(256), 0, stream>>>(q, wp_bf, proj_b, out);
}

// Round 11
// 288.098 us; speedup vs baseline: 1.3037x; 1.0045x over previous
//
#include <hip/hip_runtime.h>
#include <hip/hip_bf16.h>
#include <math.h>

constexpr int BB = 8, CCH = 192, IH = 128, IW = 128;
constexpr int WSZ = 8;
constexpr int NWIN = 256;
constexpr int NH = 6, HDIM = 32;
constexpr int NPIX = IH * IW;
constexpr int TOPK = 13107;

typedef __attribute__((ext_vector_type(8))) short bf16x8;
typedef __attribute__((ext_vector_type(4))) float f32x4;
typedef __attribute__((ext_vector_type(4))) unsigned short u16x4;
typedef __attribute__((ext_vector_type(8))) unsigned short u16x8;

__device__ __forceinline__ unsigned short f2bf(float f) {
    __hip_bfloat16 h = __float2bfloat16(f);
    return __builtin_bit_cast(unsigned short, h);
}
__device__ __forceinline__ float bf2f(unsigned short u) {
    return __uint_as_float((unsigned)u << 16);
}
__device__ __forceinline__ unsigned monot(float f) {
    unsigned u = __float_as_uint(f);
    return (u & 0x80000000u) ? ~u : (u | 0x80000000u);
}

// ---------------------------------------------------------------------------
// K1: per (b,c) row: exact top-k threshold on var (stable ties like lax.top_k),
//     masked 8x8 avg-pool + leaky_relu -> pooled (b, c, 16, 16).
//     512 threads/row; 12-bit hist PACKED u16 (2 copies, 16KB) for occupancy;
//     fused provisional-pool+collect sweep; exact candidate rank + fixup.
// ---------------------------------------------------------------------------
__global__ __launch_bounds__(512) void k1_pool(const float* __restrict__ x,
                                               const float* __restrict__ var,
                                               float* __restrict__ pooled) {
    int row = blockIdx.x;
    const float4* vrow4 = (const float4*)(var + (size_t)row * NPIX);
    const float4* xrow4 = (const float4*)(x + (size_t)row * NPIX);
    const float* xrow = x + (size_t)row * NPIX;
    int tid = threadIdx.x;
    int wv = tid >> 6, lane = tid & 63;

    constexpr int CAP = 320;
    __shared__ unsigned histP[2][2048];       // 16 KB: 4096 buckets packed 2-per-u32
    __shared__ unsigned hist256[256];         // fallback refinement
    __shared__ unsigned wtot[8];
    __shared__ unsigned s_prefix, s_rem, s_cnt, s_thr, s_need;
    __shared__ unsigned candKey[CAP], candIdx[CAP];
    __shared__ unsigned cand_cnt, eq_cnt;
    __shared__ unsigned eq_idx[64];
    __shared__ float pooled_s[256];

    for (int i = tid; i < 2 * 2048; i += 512) ((unsigned*)histP)[i] = 0;
    if (tid < 256) pooled_s[tid] = 0.f;
    if (tid == 0) { cand_cnt = 0; eq_cnt = 0; }
    __syncthreads();

    // ---- sweep 1: 12-bit histogram (packed u16 halves; max count 16384 < 65536) ----
    int hc = lane & 1;
#pragma unroll
    for (int j = 0; j < 8; ++j) {
        float4 v4 = vrow4[tid + 512 * j];
        float vv[4] = {v4.x, v4.y, v4.z, v4.w};
#pragma unroll
        for (int c = 0; c < 4; ++c) {
            unsigned bk = monot(vv[c]) >> 20;
            atomicAdd(&histP[hc][bk >> 1], 1u << ((bk & 1) << 4));
        }
    }
    __syncthreads();

    // ---- scan 4096 buckets: thread owns buckets [8*tid, 8*tid+7] (words 4*tid..) ----
    {
        unsigned h8[8]; unsigned tsum = 0;
#pragma unroll
        for (int w = 0; w < 4; ++w) {
            unsigned w0 = histP[0][tid * 4 + w];
            unsigned w1 = histP[1][tid * 4 + w];
            h8[2 * w]     = (w0 & 0xFFFFu) + (w1 & 0xFFFFu);
            h8[2 * w + 1] = (w0 >> 16) + (w1 >> 16);
            tsum += h8[2 * w] + h8[2 * w + 1];
        }
        unsigned s = tsum;                      // inclusive suffix within wave
#pragma unroll
        for (int off = 1; off < 64; off <<= 1) {
            unsigned t = __shfl(s, lane + off);
            if (lane + off < 64) s += t;
        }
        if (lane == 0) wtot[wv] = s;
        __syncthreads();
        unsigned crossTot = 0;
        for (int w = wv + 1; w < 8; ++w) crossTot += wtot[w];
        unsigned above = crossTot + (s - tsum);
        if (above < TOPK && above + tsum >= TOPK) {
            unsigned cum = above;
            for (int i = 7; i >= 0; --i) {
                if (cum < TOPK && cum + h8[i] >= TOPK) {
                    s_prefix = (unsigned)(tid * 8 + i);
                    s_rem = TOPK - cum;
                    s_cnt = h8[i];
                }
                cum += h8[i];
            }
        }
    }
    __syncthreads();

    unsigned prefix = s_prefix, rem2 = s_rem, cnt = s_cnt;
    int prefbits = 12;

    // ---- fallback refinement (normally 0 iterations) ----
    while (cnt > CAP && prefbits < 32) {
        int nb = (32 - prefbits >= 8) ? 8 : (32 - prefbits);
        int nbuck = 1 << nb;
        __syncthreads();
        for (int i = tid; i < nbuck; i += 512) hist256[i] = 0;
        __syncthreads();
        int shift = 32 - prefbits - nb;
#pragma unroll
        for (int j = 0; j < 8; ++j) {
            float4 v4 = vrow4[tid + 512 * j];
            float vv[4] = {v4.x, v4.y, v4.z, v4.w};
#pragma unroll
            for (int c = 0; c < 4; ++c) {
                unsigned mm = monot(vv[c]);
                if ((mm >> (nb + shift)) == prefix)
                    atomicAdd(&hist256[(mm >> shift) & (nbuck - 1)], 1u);
            }
        }
        __syncthreads();
        if (wv == 0) {
            int bpl = nbuck > 64 ? nbuck / 64 : 1;
            int nlanes = nbuck / bpl;
            unsigned hh[4] = {0, 0, 0, 0};
            unsigned lsum = 0;
#pragma unroll
            for (int i = 0; i < 4; ++i) {
                if (i < bpl && lane < nlanes) hh[i] = hist256[lane * bpl + i];
                lsum += hh[i];
            }
            unsigned s = lsum;
#pragma unroll
            for (int off = 1; off < 64; off <<= 1) {
                unsigned t = __shfl(s, lane + off);
                if (lane + off < 64) s += t;
            }
            unsigned above = s - lsum;
            if (lane < nlanes && above < rem2 && above + lsum >= rem2) {
                unsigned cum = above;
                for (int i = bpl - 1; i >= 0; --i) {
                    if (cum < rem2 && cum + hh[i] >= rem2) {
                        s_prefix = (prefix << nb) | (unsigned)(lane * bpl + i);
                        s_rem = rem2 - cum;
                        s_cnt = hh[i];
                    }
                    cum += hh[i];
                }
            }
        }
        __syncthreads();
        prefix = s_prefix; rem2 = s_rem; cnt = s_cnt;
        prefbits += nb;
    }

    int pshift = 32 - prefbits;

    // ---- sweep 2 (fused): provisional pooling + candidate collection ----
#pragma unroll
    for (int j = 0; j < 8; ++j) {
        float4 v4 = vrow4[tid + 512 * j];
        float4 x4 = xrow4[tid + 512 * j];
        float vv[4] = {v4.x, v4.y, v4.z, v4.w};
        float xv[4] = {x4.x, x4.y, x4.z, x4.w};
        float part = 0.f;
#pragma unroll
        for (int c = 0; c < 4; ++c) {
            unsigned mm = monot(vv[c]);
            unsigned g = (pshift == 0) ? mm : (mm >> pshift);
            float mult = (g > prefix) ? 1.0f : 0.6f;
            if (g == prefix) {
                unsigned pos = atomicAdd(&cand_cnt, 1u);
                if (pos < CAP) {
                    candKey[pos] = mm;
                    candIdx[pos] = (unsigned)(4 * tid + 2048 * j + c);
                }
            }
            part += xv[c] * mult;
        }
        part += __shfl_xor(part, 1);
        part += __shfl_xor(part, 32);
        if ((lane & 1) == 0 && lane < 32)
            atomicAdd(&pooled_s[(2 * j + (tid >> 8)) * 16 + ((tid >> 1) & 15)], part);
    }
    __syncthreads();

    // ---- exact threshold among candidates (rank via LDS broadcast) ----
    int cc = (int)min(cand_cnt, (unsigned)CAP);
    for (int ci = tid; ci < cc; ci += 512) {
        unsigned my = candKey[ci];
        unsigned kgt = 0, keq = 0;
        for (int e = 0; e < cc; ++e) {
            unsigned o = candKey[e];
            kgt += (o > my);
            keq += (o == my);
        }
        if (kgt < rem2 && kgt + keq >= rem2) {
            s_thr = my;
            s_need = rem2 - kgt;
        }
    }
    __syncthreads();
    unsigned thr = s_thr, need_eq = s_need;
    for (int ci = tid; ci < cc; ci += 512)
        if (candKey[ci] == thr) {
            unsigned pos = atomicAdd(&eq_cnt, 1u);
            if (pos < 64) eq_idx[pos] = candIdx[ci];
        }
    __syncthreads();
    int ecnt = (int)min(eq_cnt, 64u);
    if (tid == 0) {
        for (int a = 1; a < ecnt; ++a) {
            unsigned key = eq_idx[a]; int q = a - 1;
            while (q >= 0 && eq_idx[q] > key) { eq_idx[q + 1] = eq_idx[q]; --q; }
            eq_idx[q + 1] = key;
        }
    }
    __syncthreads();

    // ---- fixup: in-set candidates were pooled at 0.6 -> add 0.4*x ----
    for (int ci = tid; ci < cc; ci += 512) {
        unsigned key = candKey[ci], idx = candIdx[ci];
        bool inset;
        if (key > thr) inset = true;
        else if (key < thr) inset = false;
        else {
            unsigned rank = 0;
            for (int e = 0; e < ecnt; ++e) rank += (eq_idx[e] < idx);
            inset = (rank < need_eq);
        }
        if (inset) {
            int y = (int)(idx >> 7), xx = (int)(idx & 127);
            atomicAdd(&pooled_s[(y >> 3) * 16 + (xx >> 3)], 0.4f * xrow[idx]);
        }
    }
    __syncthreads();

    if (tid < 256) {
        float s = pooled_s[tid] * (1.0f / 64.0f);
        float pv = s > 0.f ? s : 0.01f * s;
        pooled[(size_t)row * NWIN + tid] = pv;
    }
}

// ---------------------------------------------------------------------------
// K2: per (b, window): dots with bias_w/scale_w -> sb[p][win] = {sx,sy,bx/16,by/16}
// ---------------------------------------------------------------------------
__global__ __launch_bounds__(64) void k2_sb(const float* __restrict__ pooled,
                                            const float* __restrict__ bias_w,
                                            const float* __restrict__ bias_b,
                                            const float* __restrict__ scale_w,
                                            const float* __restrict__ scale_b,
                                            float* __restrict__ sb) {
    int blk = blockIdx.x;
    int b = blk / NWIN, w = blk % NWIN;
    int tid = threadIdx.x;
    __shared__ float pcol[CCH];
    __shared__ float res[24];
    for (int c = tid; c < CCH; c += 64) pcol[c] = pooled[(size_t)(b * CCH + c) * NWIN + w];
    __syncthreads();
    if (tid < 24) {
        bool isScale = tid >= 12;
        int o = isScale ? tid - 12 : tid;
        const float* Wt = isScale ? scale_w : bias_w;
        float acc = 0.f;
        for (int c = 0; c < CCH; ++c) acc += Wt[o * CCH + c] * pcol[c];
        acc += (isScale ? scale_b[o] : bias_b[o]);
        if (!isScale) acc *= (1.0f / 16.0f);
        res[tid] = acc;
    }
    __syncthreads();
    if (tid < NH) {
        int p = b * NH + tid;
        float4 v;
        v.x = res[12 + 2 * tid];
        v.y = res[12 + 2 * tid + 1];
        v.z = res[2 * tid];
        v.w = res[2 * tid + 1];
        ((float4*)sb)[(size_t)p * NWIN + w] = v;
    }
}

// ---------------------------------------------------------------------------
// KW: convert qkv_w (110592 f32) + proj_w (36864 f32) -> bf16, concatenated.
// ---------------------------------------------------------------------------
__global__ __launch_bounds__(256) void kw_conv(const float* __restrict__ qkv_w,
                                               const float* __restrict__ proj_w,
                                               unsigned short* __restrict__ wbf) {
    int i4 = blockIdx.x * 256 + threadIdx.x;
    float4 v = (i4 < 27648) ? ((const float4*)qkv_w)[i4]
                            : ((const float4*)proj_w)[i4 - 27648];
    u16x4 pk = { f2bf(v.x), f2bf(v.y), f2bf(v.z), f2bf(v.w) };
    ((u16x4*)wbf)[i4] = pk;
}

// ---------------------------------------------------------------------------
// K0X: transpose x (b, c, px) f32 -> xt (b, px, c) bf16, LDS-tiled.
// ---------------------------------------------------------------------------
__global__ __launch_bounds__(256) void k0_xpose(const float* __restrict__ x,
                                                unsigned short* __restrict__ xt) {
    __shared__ unsigned short T[64][200];
    int px0 = blockIdx.x * 64;
    int b = blockIdx.y;
    int tid = threadIdx.x;
    int px = tid & 63, cg = tid >> 6;

#pragma unroll
    for (int j8 = 0; j8 < 6; ++j8) {
        u16x8 pk;
#pragma unroll
        for (int j = 0; j < 8; ++j)
            pk[j] = f2bf(x[(size_t)(b * CCH + cg * 48 + j8 * 8 + j) * NPIX + px0 + px]);
        *(u16x8*)&T[px][cg * 48 + j8 * 8] = pk;
    }
    __syncthreads();
#pragma unroll
    for (int i = 0; i < 6; ++i) {
        int u = tid + 256 * i;
        int p2 = u / 24, cb = u % 24;
        *(u16x8*)&xt[((size_t)(b * NPIX) + px0 + p2) * CCH + cb * 8] = *(const u16x8*)&T[p2][cb * 8];
    }
}

// ---------------------------------------------------------------------------
// K3: qkv 1x1 conv via bf16 MFMA, channel-last outputs:
//     q: (b, px, 192)   k/v: (b*NH+head, px, 32)
// ---------------------------------------------------------------------------
template <bool FAST>
__global__ __launch_bounds__(256) void k3_mfma(const float* __restrict__ x,
                                               const unsigned short* __restrict__ xt,
                                               const unsigned short* __restrict__ wq,
                                               const float* __restrict__ qkv_b,
                                               unsigned short* __restrict__ qb,
                                               unsigned short* __restrict__ kb,
                                               unsigned short* __restrict__ vb) {
    constexpr int BN = 128, KC = 64, KCP = 72;
    __shared__ unsigned short Ws[CCH][KCP];
    __shared__ unsigned short Xt[BN][KCP];
    int px0 = blockIdx.x * BN;
    int t = blockIdx.y, b = blockIdx.z;
    int o0 = t * CCH;
    int tid = threadIdx.x;
    int wv = tid >> 6, lane = tid & 63, lr = lane & 15, lg = lane >> 4;

    f32x4 acc[3][8];
#pragma unroll
    for (int i = 0; i < 3; ++i)
#pragma unroll
        for (int j = 0; j < 8; ++j) acc[i][j] = (f32x4){0.f, 0.f, 0.f, 0.f};

    int spx = tid & 127, skg = tid >> 7;

    for (int k0 = 0; k0 < CCH; k0 += KC) {
#pragma unroll
        for (int i = 0; i < 6; ++i) {
            int u = tid + 256 * i;
            int o = u >> 3, kb8 = u & 7;
            *(u16x8*)&Ws[o][kb8 * 8] = *(const u16x8*)&wq[(size_t)(o0 + o) * CCH + k0 + kb8 * 8];
        }
        if (FAST) {
#pragma unroll
            for (int i = 0; i < 4; ++i) {
                int u = tid + 256 * i;
                int px = u >> 3, kb8 = u & 7;
                *(u16x8*)&Xt[px][kb8 * 8] =
                    *(const u16x8*)&xt[((size_t)(b * NPIX) + px0 + px) * CCH + k0 + kb8 * 8];
            }
        } else {
            const float* xcol = &x[(size_t)(b * CCH + k0 + skg * 32) * NPIX + px0 + spx];
#pragma unroll
            for (int j8 = 0; j8 < 4; ++j8) {
                u16x8 pk;
#pragma unroll
                for (int j = 0; j < 8; ++j) pk[j] = f2bf(xcol[(size_t)(j8 * 8 + j) * NPIX]);
                *(u16x8*)&Xt[spx][skg * 32 + j8 * 8] = pk;
            }
        }
        __syncthreads();
#pragma unroll
        for (int kk = 0; kk < KC; kk += 32) {
            bf16x8 af[3], bfr[8];
#pragma unroll
            for (int i = 0; i < 3; ++i)
                af[i] = *(const bf16x8*)&Ws[wv * 48 + i * 16 + lr][kk + lg * 8];
#pragma unroll
            for (int j = 0; j < 8; ++j)
                bfr[j] = *(const bf16x8*)&Xt[j * 16 + lr][kk + lg * 8];
#pragma unroll
            for (int i = 0; i < 3; ++i)
#pragma unroll
                for (int j = 0; j < 8; ++j)
                    acc[i][j] = __builtin_amdgcn_mfma_f32_16x16x32_bf16(af[i], bfr[j], acc[i][j], 0, 0, 0);
        }
        __syncthreads();
    }

#pragma unroll
    for (int i = 0; i < 3; ++i) {
        int och = wv * 48 + i * 16 + lg * 4;
        float b0 = qkv_b[o0 + och], b1 = qkv_b[o0 + och + 1];
        float b2 = qkv_b[o0 + och + 2], b3 = qkv_b[o0 + och + 3];
#pragma unroll
        for (int j = 0; j < 8; ++j) {
            int px = px0 + lr + j * 16;
            u16x4 pk = { f2bf(acc[i][j][0] + b0), f2bf(acc[i][j][1] + b1),
                         f2bf(acc[i][j][2] + b2), f2bf(acc[i][j][3] + b3) };
            if (t == 0) {
                *(u16x4*)&qb[((size_t)b * NPIX + px) * CCH + och] = pk;
            } else {
                int head = och >> 5, d = och & 31;
                unsigned short* dst = (t == 1) ? kb : vb;
                *(u16x4*)&dst[(((size_t)(b * NH + head)) * NPIX + px) * HDIM + d] = pk;
            }
        }
    }
}

// ---------------------------------------------------------------------------
// K4: wave-per-window MFMA attention. S^T = K_samp . Q^T, softmax in-register,
//     PV via MFMA with P,V in LDS. Writes att (bf16, channel-last) into qb.
// ---------------------------------------------------------------------------
__global__ __launch_bounds__(256) void k4_attn(unsigned short* __restrict__ qatt,
                                               const unsigned short* __restrict__ kb,
                                               const unsigned short* __restrict__ vb,
                                               const float* __restrict__ sb,
                                               const float* __restrict__ rel_table) {
    int tid = threadIdx.x;
    int wv = tid >> 6, lane = tid & 63, lr = lane & 15, lg = lane >> 4;
    int head = blockIdx.y, b = blockIdx.z;
    int win = blockIdx.x * 4 + wv;
    int wy = win >> 4, wx = win & 15;
    int p = b * NH + head;

    __shared__ float rel_s[225];
    __shared__ unsigned short Vl[4][64][33];
    __shared__ unsigned short Pl[4][64][68];

    if (tid < 225) rel_s[tid] = rel_table[tid * NH + head];

    bf16x8 qf[4];
#pragma unroll
    for (int tq = 0; tq < 4; ++tq) {
        int q = tq * 16 + lr;
        int pix = (wy * 8 + (q >> 3)) * IW + wx * 8 + (q & 7);
        qf[tq] = *(const bf16x8*)&qatt[((size_t)b * NPIX + pix) * CCH + head * HDIM + lg * 8];
    }

    float4 sbv = ((const float4*)sb)[(size_t)p * NWIN + win];
    bf16x8 kf[4];
#pragma unroll
    for (int mi = 0; mi < 4; ++mi) {
        int px = mi * 16 + lr;
        int dy = px >> 3, dx = px & 7;
        int yg = wy * 8 + dy, xg = wx * 8 + dx;
        float gx = -1.0f + xg * (2.0f / 127.0f) + ((float)dx - 3.5f) * (2.0f / 127.0f) * sbv.x + sbv.z;
        float gy = -1.0f + yg * (2.0f / 127.0f) + ((float)dy - 3.5f) * (2.0f / 127.0f) * sbv.y + sbv.w;
        float fx = (gx + 1.0f) * 0.5f * 127.0f;
        float fy = (gy + 1.0f) * 0.5f * 127.0f;
        float x0f = floorf(fx), y0f = floorf(fy);
        float wx1 = fx - x0f, wy1 = fy - y0f;
        int ix0 = (int)x0f, iy0 = (int)y0f;
        int ix1 = ix0 + 1, iy1 = iy0 + 1;
        float w00 = (1.0f - wx1) * (1.0f - wy1);
        float w10 = wx1 * (1.0f - wy1);
        float w01 = (1.0f - wx1) * wy1;
        float w11 = wx1 * wy1;
        bool vX0 = (ix0 >= 0) && (ix0 < IW), vX1 = (ix1 >= 0) && (ix1 < IW);
        bool vY0 = (iy0 >= 0) && (iy0 < IH), vY1 = (iy1 >= 0) && (iy1 < IH);
        if (!(vX0 && vY0)) w00 = 0.f;
        if (!(vX1 && vY0)) w10 = 0.f;
        if (!(vX0 && vY1)) w01 = 0.f;
        if (!(vX1 && vY1)) w11 = 0.f;
        int cx0 = min(max(ix0, 0), IW - 1), cx1 = min(max(ix1, 0), IW - 1);
        int cy0 = min(max(iy0, 0), IH - 1), cy1 = min(max(iy1, 0), IH - 1);
        size_t r00 = ((size_t)p * NPIX + cy0 * IW + cx0) * HDIM + lg * 8;
        size_t r10 = ((size_t)p * NPIX + cy0 * IW + cx1) * HDIM + lg * 8;
        size_t r01 = ((size_t)p * NPIX + cy1 * IW + cx0) * HDIM + lg * 8;
        size_t r11 = ((size_t)p * NPIX + cy1 * IW + cx1) * HDIM + lg * 8;
        u16x8 k00 = *(const u16x8*)&kb[r00], k10 = *(const u16x8*)&kb[r10];
        u16x8 k01 = *(const u16x8*)&kb[r01], k11 = *(const u16x8*)&kb[r11];
        u16x8 v00 = *(const u16x8*)&vb[r00], v10 = *(const u16x8*)&vb[r10];
        u16x8 v01 = *(const u16x8*)&vb[r01], v11 = *(const u16x8*)&vb[r11];
#pragma unroll
        for (int c = 0; c < 8; ++c) {
            float kvv = w00 * bf2f(k00[c]) + w10 * bf2f(k10[c]) +
                        w01 * bf2f(k01[c]) + w11 * bf2f(k11[c]);
            float vvv = w00 * bf2f(v00[c]) + w10 * bf2f(v10[c]) +
                        w01 * bf2f(v01[c]) + w11 * bf2f(v11[c]);
            kf[mi][c] = (short)f2bf(kvv);
            Vl[wv][px][lg * 8 + c] = f2bf(vvv);
        }
    }

    f32x4 acc[4][4];
#pragma unroll
    for (int tk = 0; tk < 4; ++tk)
#pragma unroll
        for (int tq = 0; tq < 4; ++tq) acc[tk][tq] = (f32x4){0.f, 0.f, 0.f, 0.f};
#pragma unroll
    for (int tk = 0; tk < 4; ++tk)
#pragma unroll
        for (int tq = 0; tq < 4; ++tq)
            acc[tk][tq] = __builtin_amdgcn_mfma_f32_16x16x32_bf16(kf[tk], qf[tq], acc[tk][tq], 0, 0, 0);

    __syncthreads();

    const float scale = 0.17677669529663688f;
    int qh[4], qwv[4];
#pragma unroll
    for (int tq = 0; tq < 4; ++tq) { int q = tq * 16 + lr; qh[tq] = q >> 3; qwv[tq] = q & 7; }
    float mx[4] = {-1e30f, -1e30f, -1e30f, -1e30f};
#pragma unroll
    for (int tk = 0; tk < 4; ++tk)
#pragma unroll
        for (int r = 0; r < 4; ++r) {
            int key = tk * 16 + lg * 4 + r;
            int kh = key >> 3, kw = key & 7;
#pragma unroll
            for (int tq = 0; tq < 4; ++tq) {
                float v = acc[tk][tq][r] * scale + rel_s[(qh[tq] - kh + 7) * 15 + (qwv[tq] - kw + 7)];
                acc[tk][tq][r] = v;
                mx[tq] = fmaxf(mx[tq], v);
            }
        }
#pragma unroll
    for (int tq = 0; tq < 4; ++tq) {
        mx[tq] = fmaxf(mx[tq], __shfl_xor(mx[tq], 16));
        mx[tq] = fmaxf(mx[tq], __shfl_xor(mx[tq], 32));
    }
    float sm[4] = {0.f, 0.f, 0.f, 0.f};
#pragma unroll
    for (int tk = 0; tk < 4; ++tk)
#pragma unroll
        for (int tq = 0; tq < 4; ++tq)
#pragma unroll
            for (int r = 0; r < 4; ++r) {
                float e = __expf(acc[tk][tq][r] - mx[tq]);
                acc[tk][tq][r] = e;
                sm[tq] += e;
            }
    float inv[4];
#pragma unroll
    for (int tq = 0; tq < 4; ++tq) {
        float s = sm[tq];
        s += __shfl_xor(s, 16);
        s += __shfl_xor(s, 32);
        inv[tq] = 1.0f / s;
    }
#pragma unroll
    for (int tq = 0; tq < 4; ++tq)
#pragma unroll
        for (int tk = 0; tk < 4; ++tk) {
            u16x4 pk = { f2bf(acc[tk][tq][0] * inv[tq]), f2bf(acc[tk][tq][1] * inv[tq]),
                         f2bf(acc[tk][tq][2] * inv[tq]), f2bf(acc[tk][tq][3] * inv[tq]) };
            *(u16x4*)&Pl[wv][tq * 16 + lr][tk * 16 + lg * 4] = pk;
        }

    __syncthreads();

    f32x4 o[4][2];
#pragma unroll
    for (int mq = 0; mq < 4; ++mq)
#pragma unroll
        for (int nd = 0; nd < 2; ++nd) o[mq][nd] = (f32x4){0.f, 0.f, 0.f, 0.f};
#pragma unroll
    for (int ks = 0; ks < 2; ++ks) {
        bf16x8 Af[4];
#pragma unroll
        for (int mq = 0; mq < 4; ++mq) {
            u16x4 lo = *(const u16x4*)&Pl[wv][mq * 16 + lr][ks * 32 + lg * 8];
            u16x4 hi = *(const u16x4*)&Pl[wv][mq * 16 + lr][ks * 32 + lg * 8 + 4];
#pragma unroll
            for (int c = 0; c < 4; ++c) { Af[mq][c] = (short)lo[c]; Af[mq][c + 4] = (short)hi[c]; }
        }
        bf16x8 Bf[2];
#pragma unroll
        for (int nd = 0; nd < 2; ++nd)
#pragma unroll
            for (int j = 0; j < 8; ++j)
                Bf[nd][j] = (short)Vl[wv][ks * 32 + lg * 8 + j][nd * 16 + lr];
#pragma unroll
        for (int mq = 0; mq < 4; ++mq)
#pragma unroll
            for (int nd = 0; nd < 2; ++nd)
                o[mq][nd] = __builtin_amdgcn_mfma_f32_16x16x32_bf16(Af[mq], Bf[nd], o[mq][nd], 0, 0, 0);
    }

#pragma unroll
    for (int mq = 0; mq < 4; ++mq)
#pragma unroll
        for (int nd = 0; nd < 2; ++nd)
#pragma unroll
            for (int r = 0; r < 4; ++r) {
                int q = mq * 16 + lg * 4 + r;
                int pix = (wy * 8 + (q >> 3)) * IW + wx * 8 + (q & 7);
                qatt[((size_t)b * NPIX + pix) * CCH + head * HDIM + nd * 16 + lr] = f2bf(o[mq][nd][r]);
            }
}

// ---------------------------------------------------------------------------
// K5: projection via bf16 MFMA: out = proj_w(bf16) @ att + proj_b.
// ---------------------------------------------------------------------------
__global__ __launch_bounds__(256) void k5_mfma(const unsigned short* __restrict__ att,
                                               const unsigned short* __restrict__ wp,
                                               const float* __restrict__ proj_b,
                                               float* __restrict__ out) {
    constexpr int BN = 128, KC = 64, KCP = 72;
    __shared__ unsigned short Ws[CCH][KCP];
    __shared__ unsigned short Xt[BN][KCP];
    int px0 = blockIdx.x * BN;
    int b = blockIdx.y;
    int tid = threadIdx.x;
    int wv = tid >> 6, lane = tid & 63, lr = lane & 15, lg = lane >> 4;

    f32x4 acc[3][8];
#pragma unroll
    for (int i = 0; i < 3; ++i)
#pragma unroll
        for (int j = 0; j < 8; ++j) acc[i][j] = (f32x4){0.f, 0.f, 0.f, 0.f};

    int spx = tid & 127, skg = tid >> 7;

    for (int k0 = 0; k0 < CCH; k0 += KC) {
#pragma unroll
        for (int i = 0; i < 6; ++i) {
            int u = tid + 256 * i;
            int o = u >> 3, kb8 = u & 7;
            *(u16x8*)&Ws[o][kb8 * 8] = *(const u16x8*)&wp[(size_t)o * CCH + k0 + kb8 * 8];
        }
        {
            const unsigned short* arow = &att[((size_t)b * NPIX + px0 + spx) * CCH + k0 + skg * 32];
#pragma unroll
            for (int j8 = 0; j8 < 4; ++j8)
                *(u16x8*)&Xt[spx][skg * 32 + j8 * 8] = *(const u16x8*)&arow[j8 * 8];
        }
        __syncthreads();
#pragma unroll
        for (int kk = 0; kk < KC; kk += 32) {
            bf16x8 af[3], bfr[8];
#pragma unroll
            for (int i = 0; i < 3; ++i)
                af[i] = *(const bf16x8*)&Ws[wv * 48 + i * 16 + lr][kk + lg * 8];
#pragma unroll
            for (int j = 0; j < 8; ++j)
                bfr[j] = *(const bf16x8*)&Xt[j * 16 + lr][kk + lg * 8];
#pragma unroll
            for (int i = 0; i < 3; ++i)
#pragma unroll
                for (int j = 0; j < 8; ++j)
                    acc[i][j] = __builtin_amdgcn_mfma_f32_16x16x32_bf16(af[i], bfr[j], acc[i][j], 0, 0, 0);
        }
        __syncthreads();
    }

#pragma unroll
    for (int i = 0; i < 3; ++i) {
        int och = wv * 48 + i * 16 + lg * 4;
#pragma unroll
        for (int r = 0; r < 4; ++r) {
            float bias = proj_b[och + r];
            size_t base = (size_t)(b * CCH + och + r) * NPIX + px0 + lr;
#pragma unroll
            for (int j = 0; j < 8; ++j)
                out[base + j * 16] = acc[i][j][r] + bias;
        }
    }
}

// ---------------------------------------------------------------------------
extern "C" void kernel_launch(void* const* d_in, const int* in_sizes, int n_in,
                              void* d_out, int out_size, void* d_ws, size_t ws_size,
                              hipStream_t stream) {
    const float* x = (const float*)d_in[0];
    const float* var = (const float*)d_in[1];
    const float* qkv_w = (const float*)d_in[2];
    const float* qkv_b = (const float*)d_in[3];
    const float* bias_w = (const float*)d_in[4];
    const float* bias_b = (const float*)d_in[5];
    const float* scale_w = (const float*)d_in[6];
    const float* scale_b = (const float*)d_in[7];
    const float* proj_w = (const float*)d_in[8];
    const float* proj_b = (const float*)d_in[9];
    const float* rel_table = (const float*)d_in[10];
    float* out = (float*)d_out;

    char* ws = (char*)d_ws;
    float* pooled = (float*)ws;
    float* sb = (float*)(ws + 1572864ull);
    unsigned short* wbf = (unsigned short*)ws;            // overlaps pooled (k2 done first)
    unsigned short* wq_bf = wbf;
    unsigned short* wp_bf = wbf + 110592;
    const size_t elemQ = (size_t)BB * CCH * NPIX;
    unsigned short* q = (unsigned short*)(ws + 1769472ull);
    unsigned short* k = q + elemQ;
    unsigned short* v = k + elemQ;
    unsigned short* xt = v + elemQ;

    size_t need_base = 1769472ull + 3ull * elemQ * 2;
    size_t need_fast = 1769472ull + 4ull * elemQ * 2;
    if (ws_size < need_base) return;
    bool fast = ws_size >= need_fast;

    k1_pool<<<dim3(BB * CCH), dim3(512), 0, stream>>>(x, var, pooled);
    k2_sb<<<dim3(BB * NWIN), dim3(64), 0, stream>>>(pooled, bias_w, bias_b, scale_w, scale_b, sb);
    kw_conv<<<dim3(144), dim3(256), 0, stream>>>(qkv_w, proj_w, wbf);
    if (fast) {
        k0_xpose<<<dim3(NPIX / 64, BB), dim3(256), 0, stream>>>(x, xt);
        k3_mfma<true><<<dim3(NPIX / 128, 3, BB), dim3(256), 0, stream>>>(x, xt, wq_bf, qkv_b, q, k, v);
    } else {
        k3_mfma<false><<<dim3(NPIX / 128, 3, BB), dim3(256), 0, stream>>>(x, xt, wq_bf, qkv_b, q, k, v);
    }
    k4_attn<<<dim3(NWIN / 4, NH, BB), dim3(256), 0, stream>>>(q, k, v, sb, rel_table);
    k5_mfma<<<dim3(NPIX / 128, BB), dim3(256), 0, stream>>>(q, wp_bf, proj_b, out);
}